// Round 1
// baseline (4352.552 us; speedup 1.0000x reference)
//
#include <hip/hip_runtime.h>
#include <cstdint>
#include <cstddef>

#define N_ATOM 65536
#define E_ATOM 262144
#define N_CLQ  32768
#define E_CLQ  131072
#define BSZ    512
#define SEQ    1000

// ======================= generic tiled fp32 GEMM =======================
// C[g] = A[g] (MxK row-major, lda) @ B[g] (KxN) + bias, optional relu.
// POLICY 0: B[k][n] = Bg[k*ldb + n]                         (standard row-major)
// POLICY 1: B[k][n] = Bg[(k & cmask)*ldb + n + (k >> cshift)] (conv im2col view)
// biasMode: 0 none, 1 per-column, 2 per-row.
template<int POLICY>
__global__ __launch_bounds__(256)
void gemm_f32(const float* __restrict__ A, const float* __restrict__ B,
              float* __restrict__ C, const float* __restrict__ bias,
              int M, int N, int K, int lda, int ldb, int ldc,
              long long sA, long long sB, long long sC,
              int biasMode, int doRelu, int cmask, int cshift)
{
    __shared__ float As[16][68];   // A tile transposed: As[k][m]
    __shared__ float Bs[16][68];   // Bs[k][n]
    const int g = blockIdx.z;
    const float* __restrict__ Ag = A + (long long)g * sA;
    const float* __restrict__ Bg = B + (long long)g * sB;
    float* __restrict__ Cg = C + (long long)g * sC;
    const int gm0 = blockIdx.y * 64, gn0 = blockIdx.x * 64;
    const int t  = threadIdx.x;
    const int tx = t & 15, ty = t >> 4;
    const int al_k = t & 15, al_m = t >> 4;   // A loader: k fast (coalesced-ish)
    const int bl_n = t & 63, bl_k = t >> 6;   // B loader: n fast (coalesced)

    float acc[4][4] = {{0.f,0.f,0.f,0.f},{0.f,0.f,0.f,0.f},
                       {0.f,0.f,0.f,0.f},{0.f,0.f,0.f,0.f}};

    for (int k0 = 0; k0 < K; k0 += 16) {
#pragma unroll
        for (int i = 0; i < 4; i++) {
            int m  = al_m + i * 16;
            int gm = gm0 + m, gk = k0 + al_k;
            float v = 0.f;
            if (gm < M && gk < K) v = Ag[(long long)gm * lda + gk];
            As[al_k][m] = v;
        }
#pragma unroll
        for (int i = 0; i < 4; i++) {
            int k  = bl_k + i * 4;
            int gk = k0 + k, gn = gn0 + bl_n;
            float v = 0.f;
            if (gk < K && gn < N) {
                if (POLICY == 0) v = Bg[(long long)gk * ldb + gn];
                else             v = Bg[(gk & cmask) * ldb + gn + (gk >> cshift)];
            }
            Bs[k][bl_n] = v;
        }
        __syncthreads();
#pragma unroll
        for (int k = 0; k < 16; k++) {
            const float4 a4 = *(const float4*)&As[k][4 * ty];
            const float4 b4 = *(const float4*)&Bs[k][4 * tx];
            const float av[4] = {a4.x, a4.y, a4.z, a4.w};
            const float bv[4] = {b4.x, b4.y, b4.z, b4.w};
#pragma unroll
            for (int r = 0; r < 4; r++)
#pragma unroll
                for (int c = 0; c < 4; c++)
                    acc[r][c] = fmaf(av[r], bv[c], acc[r][c]);
        }
        __syncthreads();
    }

#pragma unroll
    for (int r = 0; r < 4; r++) {
        int row = gm0 + 4 * ty + r;
        if (row >= M) continue;
#pragma unroll
        for (int c = 0; c < 4; c++) {
            int col = gn0 + 4 * tx + c;
            if (col >= N) continue;
            float v = acc[r][c];
            if (biasMode == 1)      v += bias[col];
            else if (biasMode == 2) v += bias[row];
            if (doRelu) v = fmaxf(v, 0.f);
            Cg[(long long)row * ldc + col] = v;
        }
    }
}

// ======================= GCN helpers =======================
__global__ void count_deg(const int* __restrict__ dst, int E, int* __restrict__ deg)
{
    int i = blockIdx.x * 256 + threadIdx.x;
    if (i < E) atomicAdd(&deg[dst[i]], 1);
}

__global__ void make_dis(const int* __restrict__ deg, float* __restrict__ dis, int n)
{
    int i = blockIdx.x * 256 + threadIdx.x;
    if (i < n) dis[i] = rsqrtf((float)(deg[i] + 1));  // +1 self-loop
}

// out[v,:] = dis[v]^2 * t[v,:]   (self-loop term; also the init-write)
__global__ __launch_bounds__(128)
void agg_self(const float* __restrict__ tin, const float* __restrict__ dis,
              float* __restrict__ out, int F)
{
    int v = blockIdx.x;
    float w = dis[v] * dis[v];
    const float* ts = tin + (size_t)v * F;
    float* od = out + (size_t)v * F;
    for (int f = threadIdx.x; f < F; f += 128) od[f] = w * ts[f];
}

// out[d,:] += dis[s]*dis[d]*t[s,:] for each edge (4 edges per block, 1 wave each)
__global__ __launch_bounds__(256)
void agg_edge(const int* __restrict__ ei, int E, const float* __restrict__ tin,
              const float* __restrict__ dis, float* __restrict__ out, int F)
{
    int e = blockIdx.x * 4 + (threadIdx.x >> 6);
    if (e >= E) return;
    int s = ei[e], d = ei[E + e];
    float w = dis[s] * dis[d];
    int lane = threadIdx.x & 63;
    const float* ts = tin + (size_t)s * F;
    float* od = out + (size_t)d * F;
    for (int f = lane; f < F; f += 64) atomicAdd(&od[f], w * ts[f]);
}

__global__ __launch_bounds__(128)
void bias_act(float* __restrict__ h, const float* __restrict__ b, int F, int doRelu)
{
    int v = blockIdx.x;
    float* hv = h + (size_t)v * F;
    for (int f = threadIdx.x; f < F; f += 128) {
        float x = hv[f] + b[f];
        hv[f] = doRelu ? fmaxf(x, 0.f) : x;
    }
}

// segment max via uint atomicMax (valid: inputs are post-relu, >= 0; dst zero-init)
__global__ __launch_bounds__(128)
void pool_max(const float* __restrict__ h, const int* __restrict__ batch,
              float* __restrict__ g, int F)
{
    int v = blockIdx.x;
    int b = batch[v];
    const float* hv = h + (size_t)v * F;
    unsigned int* gu = (unsigned int*)(g + (size_t)b * F);
    for (int f = threadIdx.x; f < F; f += 128)
        atomicMax(&gu[f], __float_as_uint(hv[f]));
}

// ======================= conv branch helpers =======================
// E2[v*8+k][l] = emb[v][l+k]  (224 x 128, zero-padded)
__global__ void build_e2(const float* __restrict__ emb, float* __restrict__ e2)
{
    int idx = blockIdx.x * 256 + threadIdx.x;
    if (idx >= 224 * 128) return;
    int kf = idx >> 7, l = idx & 127;
    int v = kf >> 3, k = kf & 7;
    e2[idx] = (v < 26 && (l + k) < 128) ? emb[v * 128 + l + k] : 0.f;
}

// w2r[co][k*256+ci] = cx2W[co][ci][k]
__global__ void reorder_w2(const float* __restrict__ w, float* __restrict__ wr)
{
    int idx = blockIdx.x * 256 + threadIdx.x;
    if (idx >= 32 * 2048) return;
    int co = idx >> 11, kf = idx & 2047;
    int k = kf >> 8, ci = kf & 255;
    wr[idx] = w[(co * 256 + ci) * 8 + k];
}

// w3r[co][k*32+ci] = cx3W[co][ci][k]
__global__ void reorder_w3(const float* __restrict__ w, float* __restrict__ wr)
{
    int idx = blockIdx.x * 256 + threadIdx.x;
    if (idx >= 32 * 96) return;
    int co = idx / 96, kf = idx % 96;
    int k = kf / 32, ci = kf % 32;
    wr[idx] = w[(co * 32 + ci) * 3 + k];
}

// Wagg[b][co][v*8+k] = sum_{ci: tgt[b][ci]==v} cx1W[co][ci][k]
// grid (256 co, 32 b-chunks of 16), 64 threads = 16 b x 4 k-pairs
__global__ __launch_bounds__(64)
void scatter_wagg(const float* __restrict__ w1, const int* __restrict__ tgt,
                  float* __restrict__ wagg)
{
    int co = blockIdx.x;
    int b0 = blockIdx.y * 16;
    __shared__ float acc[16][28][8];
    __shared__ int   tg[16][256];
    int t = threadIdx.x;
    int k2 = t & 3, bi = t >> 2;

    for (int i = t; i < 16 * 28 * 8; i += 64) ((float*)acc)[i] = 0.f;
    __syncthreads();

    for (int c0 = 0; c0 < SEQ; c0 += 256) {
        int cnt = min(256, SEQ - c0);
        for (int i = t; i < 16 * 256; i += 64) {
            int r = i >> 8, c = i & 255;
            if (c < cnt) tg[r][c] = tgt[(b0 + r) * SEQ + c0 + c];
        }
        __syncthreads();
        for (int ci = 0; ci < cnt; ci++) {
            float2 wv = *(const float2*)&w1[((size_t)co * SEQ + c0 + ci) * 8 + k2 * 2];
            int tv = tg[bi][ci];
            float2* a = (float2*)&acc[bi][tv][k2 * 2];
            a->x += wv.x; a->y += wv.y;
        }
        __syncthreads();
    }
    for (int v = 0; v < 28; v++) {
        *(float2*)&wagg[((size_t)(b0 + bi) * 256 + co) * 224 + v * 8 + k2 * 2] =
            *(const float2*)&acc[bi][v][k2 * 2];
    }
}

// ======================= head =======================
__global__ __launch_bounds__(256)
void final_dot(const float* __restrict__ z, const float* __restrict__ w,
               const float* __restrict__ ob, float* __restrict__ out)
{
    int b = blockIdx.x;
    float s = 0.f;
    for (int j = threadIdx.x; j < 512; j += 256) s += z[b * 512 + j] * w[j];
    for (int off = 32; off; off >>= 1) s += __shfl_down(s, off, 64);
    __shared__ float red[4];
    if ((threadIdx.x & 63) == 0) red[threadIdx.x >> 6] = s;
    __syncthreads();
    if (threadIdx.x == 0) out[b] = red[0] + red[1] + red[2] + red[3] + ob[0];
}

// ======================= host =======================
extern "C" void kernel_launch(void* const* d_in, const int* in_sizes, int n_in,
                              void* d_out, int out_size, void* d_ws, size_t ws_size,
                              hipStream_t stream)
{
    const float* x      = (const float*)d_in[0];
    const int*   ei     = (const int*)d_in[1];
    const int*   batch  = (const int*)d_in[2];
    const float* cx     = (const float*)d_in[3];
    const int*   cei    = (const int*)d_in[4];
    const int*   cbatch = (const int*)d_in[5];
    const int*   tgt    = (const int*)d_in[6];
    const float* dW1 = (const float*)d_in[7];   const float* db1 = (const float*)d_in[8];
    const float* dW2 = (const float*)d_in[9];   const float* db2 = (const float*)d_in[10];
    const float* dW3 = (const float*)d_in[11];  const float* db3 = (const float*)d_in[12];
    const float* fcg1W = (const float*)d_in[13]; const float* fcg1b = (const float*)d_in[14];
    const float* fcg2W = (const float*)d_in[15]; const float* fcg2b = (const float*)d_in[16];
    const float* cW1 = (const float*)d_in[17];  const float* cb1 = (const float*)d_in[18];
    const float* cW2 = (const float*)d_in[19];  const float* cb2 = (const float*)d_in[20];
    const float* cW3 = (const float*)d_in[21];  const float* cb3 = (const float*)d_in[22];
    const float* cg1W = (const float*)d_in[23]; const float* cg1b = (const float*)d_in[24];
    const float* cg2W = (const float*)d_in[25]; const float* cg2b = (const float*)d_in[26];
    const float* emb  = (const float*)d_in[27];
    const float* cx1W = (const float*)d_in[28]; const float* cx1b = (const float*)d_in[29];
    const float* cx2W = (const float*)d_in[30]; const float* cx2b = (const float*)d_in[31];
    const float* cx3W = (const float*)d_in[32]; const float* cx3b = (const float*)d_in[33];
    const float* fxtW = (const float*)d_in[34]; const float* fxtb = (const float*)d_in[35];
    const float* f1W  = (const float*)d_in[36]; const float* f1b  = (const float*)d_in[37];
    const float* f2W  = (const float*)d_in[38]; const float* f2b  = (const float*)d_in[39];
    const float* oW   = (const float*)d_in[40]; const float* ob   = (const float*)d_in[41];

    char* w8 = (char*)d_ws;
    // Phase-overlapped arena: bufA/bufB for GCN phases; Wagg/c1/c2/c3 reuse it for conv.
    float* bufA = (float*)(w8);                      // 65536*404*4 = 105,906,176
    float* bufB = (float*)(w8 + 105906176);          // 105,906,176
    float* Wagg = (float*)(w8);                      // 512*256*224*4 = 117,440,512 (conv phase)
    float* c1   = (float*)(w8 + 117440512);          // 512*256*128*4 = 67,108,864
    float* c2   = (float*)(w8 + 184549376);          // 512*32*128*4  =  8,388,608
    float* c3   = (float*)(w8 + 192937984);          // 512*3584*4    =  7,340,032
    size_t off  = 211812352;
    auto take = [&](size_t bytes) -> void* {
        void* p = w8 + off;
        off += (bytes + 255) & ~(size_t)255;
        return p;
    };
    float* g0  = (float*)take(512 * 404 * 4);
    float* q0  = (float*)take(512 * 140 * 4);
    float* gh  = (float*)take(512 * 1024 * 4);
    float* qh  = (float*)take(512 * 1024 * 4);
    float* zc  = (float*)take(512 * 384 * 4);
    float* zc1 = (float*)take(512 * 1024 * 4);
    float* zc2 = (float*)take(512 * 512 * 4);
    int*   dega = (int*)take(N_ATOM * 4);
    float* disa = (float*)take(N_ATOM * 4);
    int*   degc = (int*)take(N_CLQ * 4);
    float* disc = (float*)take(N_CLQ * 4);
    float* E2   = (float*)take(224 * 128 * 4);
    float* w2r  = (float*)take(32 * 2048 * 4);
    float* w3r  = (float*)take(32 * 96 * 4);
    float* outp = (float*)d_out;

    auto gemm = [&](int policy, const float* A, const float* B, float* C,
                    const float* bias, int M, int N, int K,
                    int lda, int ldb, int ldc,
                    long long sA, long long sB, long long sC, int G,
                    int biasMode, int relu, int cmask, int cshift) {
        dim3 grid((N + 63) / 64, (M + 63) / 64, G);
        if (policy == 0)
            hipLaunchKernelGGL((gemm_f32<0>), grid, dim3(256), 0, stream,
                A, B, C, bias, M, N, K, lda, ldb, ldc, sA, sB, sC, biasMode, relu, cmask, cshift);
        else
            hipLaunchKernelGGL((gemm_f32<1>), grid, dim3(256), 0, stream,
                A, B, C, bias, M, N, K, lda, ldb, ldc, sA, sB, sC, biasMode, relu, cmask, cshift);
    };

    // ---------- init ----------
    hipMemsetAsync(dega, 0, N_ATOM * 4, stream);
    hipMemsetAsync(degc, 0, N_CLQ * 4, stream);
    hipMemsetAsync(g0, 0, 512 * 404 * 4, stream);
    hipMemsetAsync(q0, 0, 512 * 140 * 4, stream);

    // ---------- atom GCN branch ----------
    count_deg<<<(E_ATOM + 255) / 256, 256, 0, stream>>>(ei + E_ATOM, E_ATOM, dega);
    make_dis<<<(N_ATOM + 255) / 256, 256, 0, stream>>>(dega, disa, N_ATOM);

    // layer 1: t = x @ dW1 -> bufA; agg -> bufB; +b, relu
    gemm(0, x, dW1, bufA, nullptr, N_ATOM, 101, 101, 101, 101, 101, 0, 0, 0, 1, 0, 0, 0, 0);
    agg_self<<<N_ATOM, 128, 0, stream>>>(bufA, disa, bufB, 101);
    agg_edge<<<E_ATOM / 4, 256, 0, stream>>>(ei, E_ATOM, bufA, disa, bufB, 101);
    bias_act<<<N_ATOM, 128, 0, stream>>>(bufB, db1, 101, 1);
    // layer 2
    gemm(0, bufB, dW2, bufA, nullptr, N_ATOM, 202, 101, 101, 202, 202, 0, 0, 0, 1, 0, 0, 0, 0);
    agg_self<<<N_ATOM, 128, 0, stream>>>(bufA, disa, bufB, 202);
    agg_edge<<<E_ATOM / 4, 256, 0, stream>>>(ei, E_ATOM, bufA, disa, bufB, 202);
    bias_act<<<N_ATOM, 128, 0, stream>>>(bufB, db2, 202, 1);
    // layer 3
    gemm(0, bufB, dW3, bufA, nullptr, N_ATOM, 404, 202, 202, 404, 404, 0, 0, 0, 1, 0, 0, 0, 0);
    agg_self<<<N_ATOM, 128, 0, stream>>>(bufA, disa, bufB, 404);
    agg_edge<<<E_ATOM / 4, 256, 0, stream>>>(ei, E_ATOM, bufA, disa, bufB, 404);
    bias_act<<<N_ATOM, 128, 0, stream>>>(bufB, db3, 404, 1);
    // pool + FC
    pool_max<<<N_ATOM, 128, 0, stream>>>(bufB, batch, g0, 404);
    gemm(0, g0, fcg1W, gh, fcg1b, 512, 1024, 404, 404, 1024, 1024, 0, 0, 0, 1, 1, 1, 0, 0);
    gemm(0, gh, fcg2W, zc + 0, fcg2b, 512, 128, 1024, 1024, 128, 384, 0, 0, 0, 1, 1, 0, 0, 0);

    // ---------- clique GCN branch ----------
    count_deg<<<(E_CLQ + 255) / 256, 256, 0, stream>>>(cei + E_CLQ, E_CLQ, degc);
    make_dis<<<(N_CLQ + 255) / 256, 256, 0, stream>>>(degc, disc, N_CLQ);

    gemm(0, cx, cW1, bufA, nullptr, N_CLQ, 35, 35, 35, 35, 35, 0, 0, 0, 1, 0, 0, 0, 0);
    agg_self<<<N_CLQ, 128, 0, stream>>>(bufA, disc, bufB, 35);
    agg_edge<<<E_CLQ / 4, 256, 0, stream>>>(cei, E_CLQ, bufA, disc, bufB, 35);
    bias_act<<<N_CLQ, 128, 0, stream>>>(bufB, cb1, 35, 1);

    gemm(0, bufB, cW2, bufA, nullptr, N_CLQ, 70, 35, 35, 70, 70, 0, 0, 0, 1, 0, 0, 0, 0);
    agg_self<<<N_CLQ, 128, 0, stream>>>(bufA, disc, bufB, 70);
    agg_edge<<<E_CLQ / 4, 256, 0, stream>>>(cei, E_CLQ, bufA, disc, bufB, 70);
    bias_act<<<N_CLQ, 128, 0, stream>>>(bufB, cb2, 70, 1);

    gemm(0, bufB, cW3, bufA, nullptr, N_CLQ, 140, 70, 70, 140, 140, 0, 0, 0, 1, 0, 0, 0, 0);
    agg_self<<<N_CLQ, 128, 0, stream>>>(bufA, disc, bufB, 140);
    agg_edge<<<E_CLQ / 4, 256, 0, stream>>>(cei, E_CLQ, bufA, disc, bufB, 140);
    bias_act<<<N_CLQ, 128, 0, stream>>>(bufB, cb3, 140, 1);

    pool_max<<<N_CLQ, 128, 0, stream>>>(bufB, cbatch, q0, 140);
    gemm(0, q0, cg1W, qh, cg1b, 512, 1024, 140, 140, 1024, 1024, 0, 0, 0, 1, 1, 1, 0, 0);
    gemm(0, qh, cg2W, zc + 256, cg2b, 512, 128, 1024, 1024, 128, 384, 0, 0, 0, 1, 1, 0, 0, 0);

    // ---------- protein conv branch (vocab-factorized conv1) ----------
    build_e2<<<(224 * 128 + 255) / 256, 256, 0, stream>>>(emb, E2);
    reorder_w2<<<(32 * 2048 + 255) / 256, 256, 0, stream>>>(cx2W, w2r);
    reorder_w3<<<(32 * 96 + 255) / 256, 256, 0, stream>>>(cx3W, w3r);
    scatter_wagg<<<dim3(256, 32), 64, 0, stream>>>(cx1W, tgt, Wagg);

    // conv1: c1[b] (256x121) = Wagg[b] (256x224) @ E2 (224x128), + bias per row
    gemm(0, Wagg, E2, c1, cx1b, 256, 121, 224, 224, 128, 128,
         57344LL, 0LL, 32768LL, 512, 2, 0, 0, 0);
    // conv2: c2[b] (32x114) = w2r (32x2048) @ im2col(c1[b]),  kf = k*256+ci
    gemm(1, w2r, c1, c2, cx2b, 32, 114, 2048, 2048, 128, 128,
         0LL, 32768LL, 4096LL, 512, 2, 0, 255, 8);
    // conv3: c3[b] (32x112) = w3r (32x96) @ im2col(c2[b]),    kf = k*32+ci
    gemm(1, w3r, c2, c3, cx3b, 32, 112, 96, 96, 128, 112,
         0LL, 4096LL, 3584LL, 512, 2, 0, 31, 5);
    // xt = c3 (512x3584) @ fxtW -> zc cols 128..255
    gemm(0, c3, fxtW, zc + 128, fxtb, 512, 128, 3584, 3584, 128, 384,
         0, 0, 0, 1, 1, 0, 0, 0);

    // ---------- head ----------
    gemm(0, zc, f1W, zc1, f1b, 512, 1024, 384, 384, 1024, 1024, 0, 0, 0, 1, 1, 1, 0, 0);
    gemm(0, zc1, f2W, zc2, f2b, 512, 512, 1024, 1024, 512, 512, 0, 0, 0, 1, 1, 1, 0, 0);
    final_dot<<<512, 256, 0, stream>>>(zc2, oW, ob, outp);
}

// Round 2
// 3917.208 us; speedup vs baseline: 1.1111x; 1.1111x over previous
//
#include <hip/hip_runtime.h>
#include <cstdint>
#include <cstddef>

#define N_ATOM 65536
#define E_ATOM 262144
#define N_CLQ  32768
#define E_CLQ  131072
#define BSZ    512
#define SEQ    1000

// ======================= generic tiled fp32 GEMM =======================
// C[g] = A[g] (MxK row-major, lda) @ B[g] (KxN) + bias, optional relu.
// POLICY 0: B[k][n] = Bg[k*ldb + n]                         (standard row-major)
// POLICY 1: B[k][n] = Bg[(k & cmask)*ldb + n + (k >> cshift)] (conv im2col view)
// biasMode: 0 none, 1 per-column, 2 per-row.
template<int POLICY>
__global__ __launch_bounds__(256)
void gemm_f32(const float* __restrict__ A, const float* __restrict__ B,
              float* __restrict__ C, const float* __restrict__ bias,
              int M, int N, int K, int lda, int ldb, int ldc,
              long long sA, long long sB, long long sC,
              int biasMode, int doRelu, int cmask, int cshift)
{
    __shared__ float As[16][68];   // A tile transposed: As[k][m]
    __shared__ float Bs[16][68];   // Bs[k][n]
    const int g = blockIdx.z;
    const float* __restrict__ Ag = A + (long long)g * sA;
    const float* __restrict__ Bg = B + (long long)g * sB;
    float* __restrict__ Cg = C + (long long)g * sC;
    const int gm0 = blockIdx.y * 64, gn0 = blockIdx.x * 64;
    const int t  = threadIdx.x;
    const int tx = t & 15, ty = t >> 4;
    const int al_k = t & 15, al_m = t >> 4;   // A loader: k fast (coalesced-ish)
    const int bl_n = t & 63, bl_k = t >> 6;   // B loader: n fast (coalesced)

    float acc[4][4] = {{0.f,0.f,0.f,0.f},{0.f,0.f,0.f,0.f},
                       {0.f,0.f,0.f,0.f},{0.f,0.f,0.f,0.f}};

    for (int k0 = 0; k0 < K; k0 += 16) {
#pragma unroll
        for (int i = 0; i < 4; i++) {
            int m  = al_m + i * 16;
            int gm = gm0 + m, gk = k0 + al_k;
            float v = 0.f;
            if (gm < M && gk < K) v = Ag[(long long)gm * lda + gk];
            As[al_k][m] = v;
        }
#pragma unroll
        for (int i = 0; i < 4; i++) {
            int k  = bl_k + i * 4;
            int gk = k0 + k, gn = gn0 + bl_n;
            float v = 0.f;
            if (gk < K && gn < N) {
                if (POLICY == 0) v = Bg[(long long)gk * ldb + gn];
                else             v = Bg[(gk & cmask) * ldb + gn + (gk >> cshift)];
            }
            Bs[k][bl_n] = v;
        }
        __syncthreads();
#pragma unroll
        for (int k = 0; k < 16; k++) {
            const float4 a4 = *(const float4*)&As[k][4 * ty];
            const float4 b4 = *(const float4*)&Bs[k][4 * tx];
            const float av[4] = {a4.x, a4.y, a4.z, a4.w};
            const float bv[4] = {b4.x, b4.y, b4.z, b4.w};
#pragma unroll
            for (int r = 0; r < 4; r++)
#pragma unroll
                for (int c = 0; c < 4; c++)
                    acc[r][c] = fmaf(av[r], bv[c], acc[r][c]);
        }
        __syncthreads();
    }

#pragma unroll
    for (int r = 0; r < 4; r++) {
        int row = gm0 + 4 * ty + r;
        if (row >= M) continue;
#pragma unroll
        for (int c = 0; c < 4; c++) {
            int col = gn0 + 4 * tx + c;
            if (col >= N) continue;
            float v = acc[r][c];
            if (biasMode == 1)      v += bias[col];
            else if (biasMode == 2) v += bias[row];
            if (doRelu) v = fmaxf(v, 0.f);
            Cg[(long long)row * ldc + col] = v;
        }
    }
}

// ======================= GCN helpers =======================
__global__ void count_deg(const int* __restrict__ dst, int E, int* __restrict__ deg)
{
    int i = blockIdx.x * 256 + threadIdx.x;
    if (i < E) atomicAdd(&deg[dst[i]], 1);
}

__global__ void make_dis(const int* __restrict__ deg, float* __restrict__ dis, int n)
{
    int i = blockIdx.x * 256 + threadIdx.x;
    if (i < n) dis[i] = rsqrtf((float)(deg[i] + 1));  // +1 self-loop
}

// out[v,:] = dis[v]^2 * t[v,:]   (self-loop term; also the init-write)
__global__ __launch_bounds__(128)
void agg_self(const float* __restrict__ tin, const float* __restrict__ dis,
              float* __restrict__ out, int F)
{
    int v = blockIdx.x;
    float w = dis[v] * dis[v];
    const float* ts = tin + (size_t)v * F;
    float* od = out + (size_t)v * F;
    for (int f = threadIdx.x; f < F; f += 128) od[f] = w * ts[f];
}

// out[d,:] += dis[s]*dis[d]*t[s,:] for each edge (4 edges per block, 1 wave each)
__global__ __launch_bounds__(256)
void agg_edge(const int* __restrict__ ei, int E, const float* __restrict__ tin,
              const float* __restrict__ dis, float* __restrict__ out, int F)
{
    int e = blockIdx.x * 4 + (threadIdx.x >> 6);
    if (e >= E) return;
    int s = ei[e], d = ei[E + e];
    float w = dis[s] * dis[d];
    int lane = threadIdx.x & 63;
    const float* ts = tin + (size_t)s * F;
    float* od = out + (size_t)d * F;
    for (int f = lane; f < F; f += 64) atomicAdd(&od[f], w * ts[f]);
}

// segment max via uint atomicMax (valid: inputs are post-relu, >= 0; dst zero-init)
__global__ __launch_bounds__(128)
void pool_max(const float* __restrict__ h, const int* __restrict__ batch,
              float* __restrict__ g, int F)
{
    int v = blockIdx.x;
    int b = batch[v];
    const float* hv = h + (size_t)v * F;
    unsigned int* gu = (unsigned int*)(g + (size_t)b * F);
    for (int f = threadIdx.x; f < F; f += 128)
        atomicMax(&gu[f], __float_as_uint(hv[f]));
}

// ======================= conv branch helpers =======================
// E2[v*8+k][l] = emb[v][l+k]  (224 x 128, zero-padded)
__global__ void build_e2(const float* __restrict__ emb, float* __restrict__ e2)
{
    int idx = blockIdx.x * 256 + threadIdx.x;
    if (idx >= 224 * 128) return;
    int kf = idx >> 7, l = idx & 127;
    int v = kf >> 3, k = kf & 7;
    e2[idx] = (v < 26 && (l + k) < 128) ? emb[v * 128 + l + k] : 0.f;
}

// w2r[co][k*256+ci] = cx2W[co][ci][k]
__global__ void reorder_w2(const float* __restrict__ w, float* __restrict__ wr)
{
    int idx = blockIdx.x * 256 + threadIdx.x;
    if (idx >= 32 * 2048) return;
    int co = idx >> 11, kf = idx & 2047;
    int k = kf >> 8, ci = kf & 255;
    wr[idx] = w[(co * 256 + ci) * 8 + k];
}

// w3r[co][k*32+ci] = cx3W[co][ci][k]
__global__ void reorder_w3(const float* __restrict__ w, float* __restrict__ wr)
{
    int idx = blockIdx.x * 256 + threadIdx.x;
    if (idx >= 32 * 96) return;
    int co = idx / 96, kf = idx % 96;
    int k = kf / 32, ci = kf % 32;
    wr[idx] = w[(co * 32 + ci) * 3 + k];
}

// -------- counting sort of tgt[b] into 26 vocab buckets --------
// perm[b][pos] = ci, boff[b][v] bucket starts (29 entries, [26..28]=1000)
__global__ __launch_bounds__(256)
void sort_tgt(const int* __restrict__ tgt, int* __restrict__ perm,
              int* __restrict__ boff)
{
    int b = blockIdx.x;
    __shared__ int tg[SEQ];
    __shared__ int hist[32], cur[32], pre[32];
    int t = threadIdx.x;
    for (int i = t; i < SEQ; i += 256) tg[i] = tgt[b * SEQ + i];
    if (t < 32) hist[t] = 0;
    __syncthreads();
    for (int i = t; i < SEQ; i += 256) atomicAdd(&hist[tg[i]], 1);
    __syncthreads();
    if (t == 0) {
        int s = 0;
        for (int v = 0; v < 29; v++) {
            pre[v] = s; cur[v] = s;
            if (v < 26) s += hist[v];
        }
    }
    __syncthreads();
    for (int i = t; i < SEQ; i += 256) {
        int v = tg[i];
        int p = atomicAdd(&cur[v], 1);
        perm[b * SEQ + p] = i;
    }
    if (t < 29) boff[b * 29 + t] = pre[t];
}

// -------- Wagg accumulate: register acc, bucket walk --------
// Wagg[b][co][v*8+k] = sum_{ci in bucket(b,v)} cx1W[co][ci][k]
// grid (512 b, 2 co-chunks of 128), 256 threads: t>>1 = co_local, (t&1)*4 = k4
__device__ __forceinline__ void f4add(float4& a, const float4 b)
{ a.x += b.x; a.y += b.y; a.z += b.z; a.w += b.w; }

__global__ __launch_bounds__(256)
void wagg_acc(const float* __restrict__ w1, const int* __restrict__ perm,
              const int* __restrict__ boff, float* __restrict__ wagg)
{
    int b = blockIdx.x;
    int co0 = blockIdx.y * 128;
    __shared__ int pm[SEQ];
    __shared__ int off[29];
    int t = threadIdx.x;
    for (int i = t; i < SEQ; i += 256) pm[i] = perm[b * SEQ + i];
    if (t < 29) off[t] = boff[b * 29 + t];
    __syncthreads();

    int co = co0 + (t >> 1);
    int k4 = (t & 1) * 4;
    const float* wbase = w1 + (size_t)co * (SEQ * 8) + k4;
    float* wout = wagg + ((size_t)b * 256 + co) * 224 + k4;

#pragma unroll 1
    for (int v = 0; v < 28; v++) {
        float4 a0 = {0.f, 0.f, 0.f, 0.f};
        float4 a1 = {0.f, 0.f, 0.f, 0.f};
        int i = off[v], e = off[v + 1];
        for (; i + 3 < e; i += 4) {
            int c0 = pm[i], c1 = pm[i + 1], c2 = pm[i + 2], c3 = pm[i + 3];
            float4 w0 = *(const float4*)(wbase + (size_t)c0 * 8);
            float4 wv1 = *(const float4*)(wbase + (size_t)c1 * 8);
            float4 w2 = *(const float4*)(wbase + (size_t)c2 * 8);
            float4 w3 = *(const float4*)(wbase + (size_t)c3 * 8);
            f4add(a0, w0); f4add(a1, wv1); f4add(a0, w2); f4add(a1, w3);
        }
        for (; i < e; i++) {
            float4 w0 = *(const float4*)(wbase + (size_t)pm[i] * 8);
            f4add(a0, w0);
        }
        f4add(a0, a1);
        *(float4*)(wout + v * 8) = a0;
    }
}

// ======================= head =======================
__global__ __launch_bounds__(256)
void final_dot(const float* __restrict__ z, const float* __restrict__ w,
               const float* __restrict__ ob, float* __restrict__ out)
{
    int b = blockIdx.x;
    float s = 0.f;
    for (int j = threadIdx.x; j < 512; j += 256) s += z[b * 512 + j] * w[j];
    for (int off = 32; off; off >>= 1) s += __shfl_down(s, off, 64);
    __shared__ float red[4];
    if ((threadIdx.x & 63) == 0) red[threadIdx.x >> 6] = s;
    __syncthreads();
    if (threadIdx.x == 0) out[b] = red[0] + red[1] + red[2] + red[3] + ob[0];
}

// ======================= host =======================
extern "C" void kernel_launch(void* const* d_in, const int* in_sizes, int n_in,
                              void* d_out, int out_size, void* d_ws, size_t ws_size,
                              hipStream_t stream)
{
    const float* x      = (const float*)d_in[0];
    const int*   ei     = (const int*)d_in[1];
    const int*   batch  = (const int*)d_in[2];
    const float* cx     = (const float*)d_in[3];
    const int*   cei    = (const int*)d_in[4];
    const int*   cbatch = (const int*)d_in[5];
    const int*   tgt    = (const int*)d_in[6];
    const float* dW1 = (const float*)d_in[7];   const float* db1 = (const float*)d_in[8];
    const float* dW2 = (const float*)d_in[9];   const float* db2 = (const float*)d_in[10];
    const float* dW3 = (const float*)d_in[11];  const float* db3 = (const float*)d_in[12];
    const float* fcg1W = (const float*)d_in[13]; const float* fcg1b = (const float*)d_in[14];
    const float* fcg2W = (const float*)d_in[15]; const float* fcg2b = (const float*)d_in[16];
    const float* cW1 = (const float*)d_in[17];  const float* cb1 = (const float*)d_in[18];
    const float* cW2 = (const float*)d_in[19];  const float* cb2 = (const float*)d_in[20];
    const float* cW3 = (const float*)d_in[21];  const float* cb3 = (const float*)d_in[22];
    const float* cg1W = (const float*)d_in[23]; const float* cg1b = (const float*)d_in[24];
    const float* cg2W = (const float*)d_in[25]; const float* cg2b = (const float*)d_in[26];
    const float* emb  = (const float*)d_in[27];
    const float* cx1W = (const float*)d_in[28]; const float* cx1b = (const float*)d_in[29];
    const float* cx2W = (const float*)d_in[30]; const float* cx2b = (const float*)d_in[31];
    const float* cx3W = (const float*)d_in[32]; const float* cx3b = (const float*)d_in[33];
    const float* fxtW = (const float*)d_in[34]; const float* fxtb = (const float*)d_in[35];
    const float* f1W  = (const float*)d_in[36]; const float* f1b  = (const float*)d_in[37];
    const float* f2W  = (const float*)d_in[38]; const float* f2b  = (const float*)d_in[39];
    const float* oW   = (const float*)d_in[40]; const float* ob   = (const float*)d_in[41];

    char* w8 = (char*)d_ws;
    // Phase-overlapped arena: bufA/bufB for GCN phases; Wagg/c1/c2/c3 reuse it for conv.
    float* bufA = (float*)(w8);                      // 65536*404*4 = 105,906,176
    float* bufB = (float*)(w8 + 105906176);          // 105,906,176
    float* Wagg = (float*)(w8);                      // 512*256*224*4 = 117,440,512 (conv phase)
    float* c1   = (float*)(w8 + 117440512);          // 512*256*128*4 = 67,108,864
    float* c2   = (float*)(w8 + 184549376);          // 512*32*128*4  =  8,388,608
    float* c3   = (float*)(w8 + 192937984);          // 512*112*32*4  =  7,340,032 (ends 200,278,016)
    int*   perm = (int*)(w8 + 200279040);            // 512*1000*4 = 2,048,000 (conv phase only)
    int*   boff = (int*)(w8 + 202327296);            // 512*29*4 = 59,392
    size_t off  = 211812352;
    auto take = [&](size_t bytes) -> void* {
        void* p = w8 + off;
        off += (bytes + 255) & ~(size_t)255;
        return p;
    };
    float* g0  = (float*)take(512 * 404 * 4);
    float* q0  = (float*)take(512 * 140 * 4);
    float* gh  = (float*)take(512 * 1024 * 4);
    float* qh  = (float*)take(512 * 1024 * 4);
    float* zc  = (float*)take(512 * 384 * 4);
    float* zc1 = (float*)take(512 * 1024 * 4);
    float* zc2 = (float*)take(512 * 512 * 4);
    int*   dega = (int*)take(N_ATOM * 4);
    float* disa = (float*)take(N_ATOM * 4);
    int*   degc = (int*)take(N_CLQ * 4);
    float* disc = (float*)take(N_CLQ * 4);
    float* E2   = (float*)take(224 * 128 * 4);
    float* w2r  = (float*)take(32 * 2048 * 4);
    float* w3r  = (float*)take(32 * 96 * 4);
    float* outp = (float*)d_out;

    auto gemm = [&](int policy, const float* A, const float* B, float* C,
                    const float* bias, int M, int N, int K,
                    int lda, int ldb, int ldc,
                    long long sA, long long sB, long long sC, int G,
                    int biasMode, int relu, int cmask, int cshift) {
        dim3 grid((N + 63) / 64, (M + 63) / 64, G);
        if (policy == 0)
            hipLaunchKernelGGL((gemm_f32<0>), grid, dim3(256), 0, stream,
                A, B, C, bias, M, N, K, lda, ldb, ldc, sA, sB, sC, biasMode, relu, cmask, cshift);
        else
            hipLaunchKernelGGL((gemm_f32<1>), grid, dim3(256), 0, stream,
                A, B, C, bias, M, N, K, lda, ldb, ldc, sA, sB, sC, biasMode, relu, cmask, cshift);
    };

    // ---------- init ----------
    hipMemsetAsync(dega, 0, N_ATOM * 4, stream);
    hipMemsetAsync(degc, 0, N_CLQ * 4, stream);
    hipMemsetAsync(g0, 0, 512 * 404 * 4, stream);
    hipMemsetAsync(q0, 0, 512 * 140 * 4, stream);

    // ---------- atom GCN branch ----------
    // Reassociated: h_l = relu( agg(h_{l-1}) @ W + b )   [agg at F_in, bias+relu fused]
    count_deg<<<(E_ATOM + 255) / 256, 256, 0, stream>>>(ei + E_ATOM, E_ATOM, dega);
    make_dis<<<(N_ATOM + 255) / 256, 256, 0, stream>>>(dega, disa, N_ATOM);

    // layer 1: t = agg(x) [101] -> bufA; h1 = relu(t@dW1+b) -> bufB
    agg_self<<<N_ATOM, 128, 0, stream>>>(x, disa, bufA, 101);
    agg_edge<<<E_ATOM / 4, 256, 0, stream>>>(ei, E_ATOM, x, disa, bufA, 101);
    gemm(0, bufA, dW1, bufB, db1, N_ATOM, 101, 101, 101, 101, 101, 0, 0, 0, 1, 1, 1, 0, 0);
    // layer 2: agg at 101 (not 202)
    agg_self<<<N_ATOM, 128, 0, stream>>>(bufB, disa, bufA, 101);
    agg_edge<<<E_ATOM / 4, 256, 0, stream>>>(ei, E_ATOM, bufB, disa, bufA, 101);
    gemm(0, bufA, dW2, bufB, db2, N_ATOM, 202, 101, 101, 202, 202, 0, 0, 0, 1, 1, 1, 0, 0);
    // layer 3: agg at 202 (not 404)
    agg_self<<<N_ATOM, 128, 0, stream>>>(bufB, disa, bufA, 202);
    agg_edge<<<E_ATOM / 4, 256, 0, stream>>>(ei, E_ATOM, bufB, disa, bufA, 202);
    gemm(0, bufA, dW3, bufB, db3, N_ATOM, 404, 202, 202, 404, 404, 0, 0, 0, 1, 1, 1, 0, 0);
    // pool + FC
    pool_max<<<N_ATOM, 128, 0, stream>>>(bufB, batch, g0, 404);
    gemm(0, g0, fcg1W, gh, fcg1b, 512, 1024, 404, 404, 1024, 1024, 0, 0, 0, 1, 1, 1, 0, 0);
    gemm(0, gh, fcg2W, zc + 0, fcg2b, 512, 128, 1024, 1024, 128, 384, 0, 0, 0, 1, 1, 0, 0, 0);

    // ---------- clique GCN branch ----------
    count_deg<<<(E_CLQ + 255) / 256, 256, 0, stream>>>(cei + E_CLQ, E_CLQ, degc);
    make_dis<<<(N_CLQ + 255) / 256, 256, 0, stream>>>(degc, disc, N_CLQ);

    agg_self<<<N_CLQ, 128, 0, stream>>>(cx, disc, bufA, 35);
    agg_edge<<<E_CLQ / 4, 256, 0, stream>>>(cei, E_CLQ, cx, disc, bufA, 35);
    gemm(0, bufA, cW1, bufB, cb1, N_CLQ, 35, 35, 35, 35, 35, 0, 0, 0, 1, 1, 1, 0, 0);

    agg_self<<<N_CLQ, 128, 0, stream>>>(bufB, disc, bufA, 35);
    agg_edge<<<E_CLQ / 4, 256, 0, stream>>>(cei, E_CLQ, bufB, disc, bufA, 35);
    gemm(0, bufA, cW2, bufB, cb2, N_CLQ, 70, 35, 35, 70, 70, 0, 0, 0, 1, 1, 1, 0, 0);

    agg_self<<<N_CLQ, 128, 0, stream>>>(bufB, disc, bufA, 70);
    agg_edge<<<E_CLQ / 4, 256, 0, stream>>>(cei, E_CLQ, bufB, disc, bufA, 70);
    gemm(0, bufA, cW3, bufB, cb3, N_CLQ, 140, 70, 70, 140, 140, 0, 0, 0, 1, 1, 1, 0, 0);

    pool_max<<<N_CLQ, 128, 0, stream>>>(bufB, cbatch, q0, 140);
    gemm(0, q0, cg1W, qh, cg1b, 512, 1024, 140, 140, 1024, 1024, 0, 0, 0, 1, 1, 1, 0, 0);
    gemm(0, qh, cg2W, zc + 256, cg2b, 512, 128, 1024, 1024, 128, 384, 0, 0, 0, 1, 1, 0, 0, 0);

    // ---------- protein conv branch (vocab-factorized conv1) ----------
    sort_tgt<<<512, 256, 0, stream>>>(tgt, perm, boff);
    build_e2<<<(224 * 128 + 255) / 256, 256, 0, stream>>>(emb, E2);
    reorder_w2<<<(32 * 2048 + 255) / 256, 256, 0, stream>>>(cx2W, w2r);
    reorder_w3<<<(32 * 96 + 255) / 256, 256, 0, stream>>>(cx3W, w3r);
    wagg_acc<<<dim3(512, 2), 256, 0, stream>>>(cx1W, perm, boff, Wagg);

    // conv1: c1[b] (256x121) = Wagg[b] (256x224) @ E2 (224x128), + bias per row
    gemm(0, Wagg, E2, c1, cx1b, 256, 121, 224, 224, 128, 128,
         57344LL, 0LL, 32768LL, 512, 2, 0, 0, 0);
    // conv2: c2[b] (32x114) = w2r (32x2048) @ im2col(c1[b]),  kf = k*256+ci
    gemm(1, w2r, c1, c2, cx2b, 32, 114, 2048, 2048, 128, 128,
         0LL, 32768LL, 4096LL, 512, 2, 0, 255, 8);
    // conv3: c3[b] (32x112) = w3r (32x96) @ im2col(c2[b]),    kf = k*32+ci
    gemm(1, w3r, c2, c3, cx3b, 32, 112, 96, 96, 128, 112,
         0LL, 4096LL, 3584LL, 512, 2, 0, 31, 5);
    // xt = c3 (512x3584) @ fxtW -> zc cols 128..255
    gemm(0, c3, fxtW, zc + 128, fxtb, 512, 128, 3584, 3584, 128, 384,
         0, 0, 0, 1, 1, 0, 0, 0);

    // ---------- head ----------
    gemm(0, zc, f1W, zc1, f1b, 512, 1024, 384, 384, 1024, 1024, 0, 0, 0, 1, 1, 1, 0, 0);
    gemm(0, zc1, f2W, zc2, f2b, 512, 512, 1024, 1024, 512, 512, 0, 0, 0, 1, 1, 1, 0, 0);
    final_dot<<<512, 256, 0, stream>>>(zc2, oW, ob, outp);
}

// Round 3
// 2730.184 us; speedup vs baseline: 1.5942x; 1.4348x over previous
//
#include <hip/hip_runtime.h>
#include <cstdint>
#include <cstddef>

#define N_ATOM 65536
#define E_ATOM 262144
#define N_CLQ  32768
#define E_CLQ  131072
#define BSZ    512
#define SEQ    1000

typedef __attribute__((ext_vector_type(8))) short short8;
typedef __attribute__((ext_vector_type(4))) float f32x4;

__device__ __forceinline__ unsigned short f2bf(float x) {
    unsigned int u = __float_as_uint(x);
    u += 0x7FFFu + ((u >> 16) & 1u);          // round-to-nearest-even
    return (unsigned short)(u >> 16);
}

// ======================= bf16 MFMA GEMM =======================
// C[g] = A[g] (MxK fp32 row-major) @ B[g] (KxN fp32) + bias, optional relu.
// POLICY 0: B[k][n] = Bg[k*ldb + n]
// POLICY 1: B[k][n] = Bg[(k & cmask)*ldb + n + (k >> cshift)]  (conv im2col view)
// Block: 256 thr = 4 waves (2x2), wave tile 32x32 (2x2 mfma 16x16x32), block tile 64x64.
template<int POLICY>
__global__ __launch_bounds__(256)
void gemm_mf(const float* __restrict__ A, const float* __restrict__ B,
             float* __restrict__ C, const float* __restrict__ bias,
             int M, int N, int K, int lda, int ldb, int ldc,
             long long sA, long long sB, long long sC,
             int biasMode, int doRelu, int cmask, int cshift)
{
    __shared__ __align__(16) unsigned short As[64][40];  // [m][k] pad 40 (80B rows)
    __shared__ __align__(16) unsigned short Bs[64][40];  // [n][k] (transposed in)
    const int g = blockIdx.z;
    const float* __restrict__ Ag = A + (long long)g * sA;
    const float* __restrict__ Bg = B + (long long)g * sB;
    float* __restrict__ Cg = C + (long long)g * sC;
    const int gm0 = blockIdx.y * 64, gn0 = blockIdx.x * 64;
    const int t = threadIdx.x;
    const int lane = t & 63, wv = t >> 6, wm = wv >> 1, wn = wv & 1;
    const int lr = lane & 15, kb = (lane >> 4) * 8;
    const int am = t >> 2,  ak = (t & 3) * 8;    // A stager: row am, 8 k's at ak
    const int bn = t & 63,  bk = (t >> 6) * 8;   // B stager: col bn, 8 k's at bk

    f32x4 acc[2][2] = {};

    for (int k0 = 0; k0 < K; k0 += 32) {
        { // stage A tile (fp32 -> bf16)
            int gm = gm0 + am;
            unsigned int p[4];
#pragma unroll
            for (int j2 = 0; j2 < 4; j2++) {
                float v0 = 0.f, v1 = 0.f;
                int gk0 = k0 + ak + j2 * 2, gk1 = gk0 + 1;
                if (gm < M) {
                    if (gk0 < K) v0 = Ag[(long long)gm * lda + gk0];
                    if (gk1 < K) v1 = Ag[(long long)gm * lda + gk1];
                }
                p[j2] = (unsigned int)f2bf(v0) | ((unsigned int)f2bf(v1) << 16);
            }
            *(uint4*)&As[am][ak] = make_uint4(p[0], p[1], p[2], p[3]);
        }
        { // stage B tile transposed (fp32 -> bf16), coalesced along n
            int gn = gn0 + bn;
            unsigned int p[4];
#pragma unroll
            for (int j2 = 0; j2 < 4; j2++) {
                float v0 = 0.f, v1 = 0.f;
                int gk0 = k0 + bk + j2 * 2, gk1 = gk0 + 1;
                if (gn < N) {
                    if (gk0 < K)
                        v0 = (POLICY == 0) ? Bg[(long long)gk0 * ldb + gn]
                                           : Bg[(long long)(gk0 & cmask) * ldb + gn + (gk0 >> cshift)];
                    if (gk1 < K)
                        v1 = (POLICY == 0) ? Bg[(long long)gk1 * ldb + gn]
                                           : Bg[(long long)(gk1 & cmask) * ldb + gn + (gk1 >> cshift)];
                }
                p[j2] = (unsigned int)f2bf(v0) | ((unsigned int)f2bf(v1) << 16);
            }
            *(uint4*)&Bs[bn][bk] = make_uint4(p[0], p[1], p[2], p[3]);
        }
        __syncthreads();
        short8 a0 = __builtin_bit_cast(short8, *(const uint4*)&As[wm * 32 + lr][kb]);
        short8 a1 = __builtin_bit_cast(short8, *(const uint4*)&As[wm * 32 + 16 + lr][kb]);
        short8 b0 = __builtin_bit_cast(short8, *(const uint4*)&Bs[wn * 32 + lr][kb]);
        short8 b1 = __builtin_bit_cast(short8, *(const uint4*)&Bs[wn * 32 + 16 + lr][kb]);
        acc[0][0] = __builtin_amdgcn_mfma_f32_16x16x32_bf16(a0, b0, acc[0][0], 0, 0, 0);
        acc[0][1] = __builtin_amdgcn_mfma_f32_16x16x32_bf16(a0, b1, acc[0][1], 0, 0, 0);
        acc[1][0] = __builtin_amdgcn_mfma_f32_16x16x32_bf16(a1, b0, acc[1][0], 0, 0, 0);
        acc[1][1] = __builtin_amdgcn_mfma_f32_16x16x32_bf16(a1, b1, acc[1][1], 0, 0, 0);
        __syncthreads();
    }

#pragma unroll
    for (int fm = 0; fm < 2; fm++) {
#pragma unroll
        for (int ri = 0; ri < 4; ri++) {
            int row = gm0 + wm * 32 + fm * 16 + (lane >> 4) * 4 + ri;
            if (row >= M) continue;
#pragma unroll
            for (int fn = 0; fn < 2; fn++) {
                int col = gn0 + wn * 32 + fn * 16 + lr;
                if (col >= N) continue;
                float v = acc[fm][fn][ri];
                if (biasMode == 1)      v += bias[col];
                else if (biasMode == 2) v += bias[row];
                if (doRelu) v = fmaxf(v, 0.f);
                Cg[(long long)row * ldc + col] = v;
            }
        }
    }
}

// ======================= GCN helpers =======================
__global__ void count_deg(const int* __restrict__ dst, int E, int* __restrict__ deg)
{
    int i = blockIdx.x * 256 + threadIdx.x;
    if (i < E) atomicAdd(&deg[dst[i]], 1);
}

__global__ void make_dis(const int* __restrict__ deg, float* __restrict__ dis, int n)
{
    int i = blockIdx.x * 256 + threadIdx.x;
    if (i < n) dis[i] = rsqrtf((float)(deg[i] + 1));  // +1 self-loop
}

__global__ __launch_bounds__(128)
void agg_self(const float* __restrict__ tin, const float* __restrict__ dis,
              float* __restrict__ out, int F)
{
    int v = blockIdx.x;
    float w = dis[v] * dis[v];
    const float* ts = tin + (size_t)v * F;
    float* od = out + (size_t)v * F;
    for (int f = threadIdx.x; f < F; f += 128) od[f] = w * ts[f];
}

__global__ __launch_bounds__(256)
void agg_edge(const int* __restrict__ ei, int E, const float* __restrict__ tin,
              const float* __restrict__ dis, float* __restrict__ out, int F)
{
    int e = blockIdx.x * 4 + (threadIdx.x >> 6);
    if (e >= E) return;
    int s = ei[e], d = ei[E + e];
    float w = dis[s] * dis[d];
    int lane = threadIdx.x & 63;
    const float* ts = tin + (size_t)s * F;
    float* od = out + (size_t)d * F;
    for (int f = lane; f < F; f += 64) atomicAdd(&od[f], w * ts[f]);
}

// segment max via uint atomicMax (inputs post-relu >= 0; dst zero-init)
__global__ __launch_bounds__(128)
void pool_max(const float* __restrict__ h, const int* __restrict__ batch,
              float* __restrict__ g, int F)
{
    int v = blockIdx.x;
    int b = batch[v];
    const float* hv = h + (size_t)v * F;
    unsigned int* gu = (unsigned int*)(g + (size_t)b * F);
    for (int f = threadIdx.x; f < F; f += 128)
        atomicMax(&gu[f], __float_as_uint(hv[f]));
}

// ======================= conv branch helpers =======================
__global__ void build_e2(const float* __restrict__ emb, float* __restrict__ e2)
{
    int idx = blockIdx.x * 256 + threadIdx.x;
    if (idx >= 224 * 128) return;
    int kf = idx >> 7, l = idx & 127;
    int v = kf >> 3, k = kf & 7;
    e2[idx] = (v < 26 && (l + k) < 128) ? emb[v * 128 + l + k] : 0.f;
}

__global__ void reorder_w2(const float* __restrict__ w, float* __restrict__ wr)
{
    int idx = blockIdx.x * 256 + threadIdx.x;
    if (idx >= 32 * 2048) return;
    int co = idx >> 11, kf = idx & 2047;
    int k = kf >> 8, ci = kf & 255;
    wr[idx] = w[(co * 256 + ci) * 8 + k];
}

__global__ void reorder_w3(const float* __restrict__ w, float* __restrict__ wr)
{
    int idx = blockIdx.x * 256 + threadIdx.x;
    if (idx >= 32 * 96) return;
    int co = idx / 96, kf = idx % 96;
    int k = kf / 32, ci = kf % 32;
    wr[idx] = w[(co * 32 + ci) * 3 + k];
}

// counting sort of tgt[b] into 26 vocab buckets
__global__ __launch_bounds__(256)
void sort_tgt(const int* __restrict__ tgt, int* __restrict__ perm,
              int* __restrict__ boff)
{
    int b = blockIdx.x;
    __shared__ int tg[SEQ];
    __shared__ int hist[32], cur[32], pre[32];
    int t = threadIdx.x;
    for (int i = t; i < SEQ; i += 256) tg[i] = tgt[b * SEQ + i];
    if (t < 32) hist[t] = 0;
    __syncthreads();
    for (int i = t; i < SEQ; i += 256) atomicAdd(&hist[tg[i]], 1);
    __syncthreads();
    if (t == 0) {
        int s = 0;
        for (int v = 0; v < 29; v++) {
            pre[v] = s; cur[v] = s;
            if (v < 26) s += hist[v];
        }
    }
    __syncthreads();
    for (int i = t; i < SEQ; i += 256) {
        int v = tg[i];
        int p = atomicAdd(&cur[v], 1);
        perm[b * SEQ + p] = i;
    }
    if (t < 29) boff[b * 29 + t] = pre[t];
}

// Wagg[b][co][v*8+k] = sum_{ci in bucket(b,v)} w1[co][ci][k]
// grid (256 co, 4 b-chunks of 128). w1[co] slice (32 KB) staged in LDS once.
__global__ __launch_bounds__(256)
void wagg_acc2(const float* __restrict__ w1, const int* __restrict__ perm,
               const int* __restrict__ boff, float* __restrict__ wagg)
{
    int co = blockIdx.x;
    int b0 = blockIdx.y * 128;
    __shared__ float w[8000];   // w1[co][ci][k]
    __shared__ int pm[SEQ];
    __shared__ int off[32];
    int t = threadIdx.x;
    for (int i = t; i < 8000; i += 256) w[i] = w1[(size_t)co * 8000 + i];
    int v = t >> 3, k = t & 7;  // 224 active compute threads
    for (int bi = 0; bi < 128; bi++) {
        int b = b0 + bi;
        __syncthreads();        // protect pm/off from previous iteration readers
        for (int i = t; i < SEQ; i += 256) pm[i] = perm[b * SEQ + i];
        if (t < 29) off[t] = boff[b * 29 + t];
        __syncthreads();
        if (v < 28) {
            float a = 0.f;
            int e = off[v + 1];
            for (int i = off[v]; i < e; i++) a += w[pm[i] * 8 + k];
            wagg[((size_t)b * 256 + co) * 224 + t] = a;
        }
    }
}

// ======================= head =======================
__global__ __launch_bounds__(256)
void final_dot(const float* __restrict__ z, const float* __restrict__ w,
               const float* __restrict__ ob, float* __restrict__ out)
{
    int b = blockIdx.x;
    float s = 0.f;
    for (int j = threadIdx.x; j < 512; j += 256) s += z[b * 512 + j] * w[j];
    for (int off = 32; off; off >>= 1) s += __shfl_down(s, off, 64);
    __shared__ float red[4];
    if ((threadIdx.x & 63) == 0) red[threadIdx.x >> 6] = s;
    __syncthreads();
    if (threadIdx.x == 0) out[b] = red[0] + red[1] + red[2] + red[3] + ob[0];
}

// ======================= host =======================
extern "C" void kernel_launch(void* const* d_in, const int* in_sizes, int n_in,
                              void* d_out, int out_size, void* d_ws, size_t ws_size,
                              hipStream_t stream)
{
    const float* x      = (const float*)d_in[0];
    const int*   ei     = (const int*)d_in[1];
    const int*   batch  = (const int*)d_in[2];
    const float* cx     = (const float*)d_in[3];
    const int*   cei    = (const int*)d_in[4];
    const int*   cbatch = (const int*)d_in[5];
    const int*   tgt    = (const int*)d_in[6];
    const float* dW1 = (const float*)d_in[7];   const float* db1 = (const float*)d_in[8];
    const float* dW2 = (const float*)d_in[9];   const float* db2 = (const float*)d_in[10];
    const float* dW3 = (const float*)d_in[11];  const float* db3 = (const float*)d_in[12];
    const float* fcg1W = (const float*)d_in[13]; const float* fcg1b = (const float*)d_in[14];
    const float* fcg2W = (const float*)d_in[15]; const float* fcg2b = (const float*)d_in[16];
    const float* cW1 = (const float*)d_in[17];  const float* cb1 = (const float*)d_in[18];
    const float* cW2 = (const float*)d_in[19];  const float* cb2 = (const float*)d_in[20];
    const float* cW3 = (const float*)d_in[21];  const float* cb3 = (const float*)d_in[22];
    const float* cg1W = (const float*)d_in[23]; const float* cg1b = (const float*)d_in[24];
    const float* cg2W = (const float*)d_in[25]; const float* cg2b = (const float*)d_in[26];
    const float* emb  = (const float*)d_in[27];
    const float* cx1W = (const float*)d_in[28]; const float* cx1b = (const float*)d_in[29];
    const float* cx2W = (const float*)d_in[30]; const float* cx2b = (const float*)d_in[31];
    const float* cx3W = (const float*)d_in[32]; const float* cx3b = (const float*)d_in[33];
    const float* fxtW = (const float*)d_in[34]; const float* fxtb = (const float*)d_in[35];
    const float* f1W  = (const float*)d_in[36]; const float* f1b  = (const float*)d_in[37];
    const float* f2W  = (const float*)d_in[38]; const float* f2b  = (const float*)d_in[39];
    const float* oW   = (const float*)d_in[40]; const float* ob   = (const float*)d_in[41];

    char* w8 = (char*)d_ws;
    float* bufA = (float*)(w8);                      // 65536*404*4 = 105,906,176
    float* bufB = (float*)(w8 + 105906176);          // 105,906,176
    float* Wagg = (float*)(w8);                      // 512*256*224*4 = 117,440,512 (conv phase)
    float* c1   = (float*)(w8 + 117440512);          // 512*256*128*4 = 67,108,864
    float* c2   = (float*)(w8 + 184549376);          // 512*32*128*4  =  8,388,608
    float* c3   = (float*)(w8 + 192937984);          // 512*112*32*4  =  7,340,032
    int*   perm = (int*)(w8 + 200279040);            // 512*1000*4
    int*   boff = (int*)(w8 + 202327296);            // 512*29*4
    size_t off  = 211812352;
    auto take = [&](size_t bytes) -> void* {
        void* p = w8 + off;
        off += (bytes + 255) & ~(size_t)255;
        return p;
    };
    float* g0  = (float*)take(512 * 404 * 4);
    float* q0  = (float*)take(512 * 140 * 4);
    float* gh  = (float*)take(512 * 1024 * 4);
    float* qh  = (float*)take(512 * 1024 * 4);
    float* zc  = (float*)take(512 * 384 * 4);
    float* zc1 = (float*)take(512 * 1024 * 4);
    float* zc2 = (float*)take(512 * 512 * 4);
    int*   dega = (int*)take(N_ATOM * 4);
    float* disa = (float*)take(N_ATOM * 4);
    int*   degc = (int*)take(N_CLQ * 4);
    float* disc = (float*)take(N_CLQ * 4);
    float* E2   = (float*)take(224 * 128 * 4);
    float* w2r  = (float*)take(32 * 2048 * 4);
    float* w3r  = (float*)take(32 * 96 * 4);
    float* outp = (float*)d_out;

    auto gemm = [&](int policy, const float* A, const float* B, float* C,
                    const float* bias, int M, int N, int K,
                    int lda, int ldb, int ldc,
                    long long sA, long long sB, long long sC, int G,
                    int biasMode, int relu, int cmask, int cshift) {
        dim3 grid((N + 63) / 64, (M + 63) / 64, G);
        if (policy == 0)
            hipLaunchKernelGGL((gemm_mf<0>), grid, dim3(256), 0, stream,
                A, B, C, bias, M, N, K, lda, ldb, ldc, sA, sB, sC, biasMode, relu, cmask, cshift);
        else
            hipLaunchKernelGGL((gemm_mf<1>), grid, dim3(256), 0, stream,
                A, B, C, bias, M, N, K, lda, ldb, ldc, sA, sB, sC, biasMode, relu, cmask, cshift);
    };

    // ---------- init ----------
    hipMemsetAsync(dega, 0, N_ATOM * 4, stream);
    hipMemsetAsync(degc, 0, N_CLQ * 4, stream);
    hipMemsetAsync(g0, 0, 512 * 404 * 4, stream);
    hipMemsetAsync(q0, 0, 512 * 140 * 4, stream);

    // ---------- atom GCN branch (agg at F_in, bias+relu fused into GEMM) ----------
    count_deg<<<(E_ATOM + 255) / 256, 256, 0, stream>>>(ei + E_ATOM, E_ATOM, dega);
    make_dis<<<(N_ATOM + 255) / 256, 256, 0, stream>>>(dega, disa, N_ATOM);

    agg_self<<<N_ATOM, 128, 0, stream>>>(x, disa, bufA, 101);
    agg_edge<<<E_ATOM / 4, 256, 0, stream>>>(ei, E_ATOM, x, disa, bufA, 101);
    gemm(0, bufA, dW1, bufB, db1, N_ATOM, 101, 101, 101, 101, 101, 0, 0, 0, 1, 1, 1, 0, 0);

    agg_self<<<N_ATOM, 128, 0, stream>>>(bufB, disa, bufA, 101);
    agg_edge<<<E_ATOM / 4, 256, 0, stream>>>(ei, E_ATOM, bufB, disa, bufA, 101);
    gemm(0, bufA, dW2, bufB, db2, N_ATOM, 202, 101, 101, 202, 202, 0, 0, 0, 1, 1, 1, 0, 0);

    agg_self<<<N_ATOM, 128, 0, stream>>>(bufB, disa, bufA, 202);
    agg_edge<<<E_ATOM / 4, 256, 0, stream>>>(ei, E_ATOM, bufB, disa, bufA, 202);
    gemm(0, bufA, dW3, bufB, db3, N_ATOM, 404, 202, 202, 404, 404, 0, 0, 0, 1, 1, 1, 0, 0);

    pool_max<<<N_ATOM, 128, 0, stream>>>(bufB, batch, g0, 404);
    gemm(0, g0, fcg1W, gh, fcg1b, 512, 1024, 404, 404, 1024, 1024, 0, 0, 0, 1, 1, 1, 0, 0);
    gemm(0, gh, fcg2W, zc + 0, fcg2b, 512, 128, 1024, 1024, 128, 384, 0, 0, 0, 1, 1, 0, 0, 0);

    // ---------- clique GCN branch ----------
    count_deg<<<(E_CLQ + 255) / 256, 256, 0, stream>>>(cei + E_CLQ, E_CLQ, degc);
    make_dis<<<(N_CLQ + 255) / 256, 256, 0, stream>>>(degc, disc, N_CLQ);

    agg_self<<<N_CLQ, 128, 0, stream>>>(cx, disc, bufA, 35);
    agg_edge<<<E_CLQ / 4, 256, 0, stream>>>(cei, E_CLQ, cx, disc, bufA, 35);
    gemm(0, bufA, cW1, bufB, cb1, N_CLQ, 35, 35, 35, 35, 35, 0, 0, 0, 1, 1, 1, 0, 0);

    agg_self<<<N_CLQ, 128, 0, stream>>>(bufB, disc, bufA, 35);
    agg_edge<<<E_CLQ / 4, 256, 0, stream>>>(cei, E_CLQ, bufB, disc, bufA, 35);
    gemm(0, bufA, cW2, bufB, cb2, N_CLQ, 70, 35, 35, 70, 70, 0, 0, 0, 1, 1, 1, 0, 0);

    agg_self<<<N_CLQ, 128, 0, stream>>>(bufB, disc, bufA, 70);
    agg_edge<<<E_CLQ / 4, 256, 0, stream>>>(cei, E_CLQ, bufB, disc, bufA, 70);
    gemm(0, bufA, cW3, bufB, cb3, N_CLQ, 140, 70, 70, 140, 140, 0, 0, 0, 1, 1, 1, 0, 0);

    pool_max<<<N_CLQ, 128, 0, stream>>>(bufB, cbatch, q0, 140);
    gemm(0, q0, cg1W, qh, cg1b, 512, 1024, 140, 140, 1024, 1024, 0, 0, 0, 1, 1, 1, 0, 0);
    gemm(0, qh, cg2W, zc + 256, cg2b, 512, 128, 1024, 1024, 128, 384, 0, 0, 0, 1, 1, 0, 0, 0);

    // ---------- protein conv branch (vocab-factorized conv1) ----------
    sort_tgt<<<512, 256, 0, stream>>>(tgt, perm, boff);
    build_e2<<<(224 * 128 + 255) / 256, 256, 0, stream>>>(emb, E2);
    reorder_w2<<<(32 * 2048 + 255) / 256, 256, 0, stream>>>(cx2W, w2r);
    reorder_w3<<<(32 * 96 + 255) / 256, 256, 0, stream>>>(cx3W, w3r);
    wagg_acc2<<<dim3(256, 4), 256, 0, stream>>>(cx1W, perm, boff, Wagg);

    // conv1: c1[b] (256x121) = Wagg[b] (256x224) @ E2 (224x128), bias per row
    gemm(0, Wagg, E2, c1, cx1b, 256, 121, 224, 224, 128, 128,
         57344LL, 0LL, 32768LL, 512, 2, 0, 0, 0);
    // conv2: c2[b] (32x114) = w2r (32x2048) @ im2col(c1[b]),  k = kk*256+ci
    gemm(1, w2r, c1, c2, cx2b, 32, 114, 2048, 2048, 128, 128,
         0LL, 32768LL, 4096LL, 512, 2, 0, 255, 8);
    // conv3: c3[b] (32x112) = w3r (32x96) @ im2col(c2[b]),    k = kk*32+ci
    gemm(1, w3r, c2, c3, cx3b, 32, 112, 96, 96, 128, 112,
         0LL, 4096LL, 3584LL, 512, 2, 0, 31, 5);
    // xt = c3 (512x3584) @ fxtW -> zc cols 128..255
    gemm(0, c3, fxtW, zc + 128, fxtb, 512, 128, 3584, 3584, 128, 384,
         0, 0, 0, 1, 1, 0, 0, 0);

    // ---------- head ----------
    gemm(0, zc, f1W, zc1, f1b, 512, 1024, 384, 384, 1024, 1024, 0, 0, 0, 1, 1, 1, 0, 0);
    gemm(0, zc1, f2W, zc2, f2b, 512, 512, 1024, 1024, 512, 512, 0, 0, 0, 1, 1, 1, 0, 0);
    final_dot<<<512, 256, 0, stream>>>(zc2, oW, ob, outp);
}

// Round 5
// 2449.806 us; speedup vs baseline: 1.7767x; 1.1144x over previous
//
#include <hip/hip_runtime.h>
#include <cstdint>
#include <cstddef>

#define N_ATOM 65536
#define E_ATOM 262144
#define N_CLQ  32768
#define E_CLQ  131072
#define BSZ    512
#define SEQ    1000

typedef __attribute__((ext_vector_type(8))) short short8;
typedef __attribute__((ext_vector_type(4))) float f32x4;

__device__ __forceinline__ unsigned short f2bf(float x) {
    unsigned int u = __float_as_uint(x);
    u += 0x7FFFu + ((u >> 16) & 1u);          // round-to-nearest-even
    return (unsigned short)(u >> 16);
}

// ======================= bf16 MFMA GEMM =======================
// C[g] = A[g] (MxK fp32 row-major) @ B[g] (KxN fp32) + bias, optional relu.
// POLICY 0: B[k][n] = Bg[k*ldb + n]
// POLICY 1: B[k][n] = Bg[(k & cmask)*ldb + n + (k >> cshift)]  (conv im2col view)
// Block: 256 thr = 4 waves (2x2), wave tile 32x32 (2x2 mfma 16x16x32), block tile 64x64.
template<int POLICY>
__global__ __launch_bounds__(256)
void gemm_mf(const float* __restrict__ A, const float* __restrict__ B,
             float* __restrict__ C, const float* __restrict__ bias,
             int M, int N, int K, int lda, int ldb, int ldc,
             long long sA, long long sB, long long sC,
             int biasMode, int doRelu, int cmask, int cshift)
{
    __shared__ __align__(16) unsigned short As[64][40];  // [m][k] pad 40 (80B rows)
    __shared__ __align__(16) unsigned short Bs[64][40];  // [n][k] (transposed in)
    const int g = blockIdx.z;
    const float* __restrict__ Ag = A + (long long)g * sA;
    const float* __restrict__ Bg = B + (long long)g * sB;
    float* __restrict__ Cg = C + (long long)g * sC;
    const int gm0 = blockIdx.y * 64, gn0 = blockIdx.x * 64;
    const int t = threadIdx.x;
    const int lane = t & 63, wv = t >> 6, wm = wv >> 1, wn = wv & 1;
    const int lr = lane & 15, kb = (lane >> 4) * 8;
    const int am = t >> 2,  ak = (t & 3) * 8;    // A stager: row am, 8 k's at ak
    const int bn = t & 63,  bk = (t >> 6) * 8;   // B stager: col bn, 8 k's at bk

    f32x4 acc[2][2] = {};

    for (int k0 = 0; k0 < K; k0 += 32) {
        { // stage A tile (fp32 -> bf16)
            int gm = gm0 + am;
            unsigned int p[4];
#pragma unroll
            for (int j2 = 0; j2 < 4; j2++) {
                float v0 = 0.f, v1 = 0.f;
                int gk0 = k0 + ak + j2 * 2, gk1 = gk0 + 1;
                if (gm < M) {
                    if (gk0 < K) v0 = Ag[(long long)gm * lda + gk0];
                    if (gk1 < K) v1 = Ag[(long long)gm * lda + gk1];
                }
                p[j2] = (unsigned int)f2bf(v0) | ((unsigned int)f2bf(v1) << 16);
            }
            *(uint4*)&As[am][ak] = make_uint4(p[0], p[1], p[2], p[3]);
        }
        { // stage B tile transposed (fp32 -> bf16), coalesced along n
            int gn = gn0 + bn;
            unsigned int p[4];
#pragma unroll
            for (int j2 = 0; j2 < 4; j2++) {
                float v0 = 0.f, v1 = 0.f;
                int gk0 = k0 + bk + j2 * 2, gk1 = gk0 + 1;
                if (gn < N) {
                    if (gk0 < K)
                        v0 = (POLICY == 0) ? Bg[(long long)gk0 * ldb + gn]
                                           : Bg[(long long)(gk0 & cmask) * ldb + gn + (gk0 >> cshift)];
                    if (gk1 < K)
                        v1 = (POLICY == 0) ? Bg[(long long)gk1 * ldb + gn]
                                           : Bg[(long long)(gk1 & cmask) * ldb + gn + (gk1 >> cshift)];
                }
                p[j2] = (unsigned int)f2bf(v0) | ((unsigned int)f2bf(v1) << 16);
            }
            *(uint4*)&Bs[bn][bk] = make_uint4(p[0], p[1], p[2], p[3]);
        }
        __syncthreads();
        short8 a0 = __builtin_bit_cast(short8, *(const uint4*)&As[wm * 32 + lr][kb]);
        short8 a1 = __builtin_bit_cast(short8, *(const uint4*)&As[wm * 32 + 16 + lr][kb]);
        short8 b0 = __builtin_bit_cast(short8, *(const uint4*)&Bs[wn * 32 + lr][kb]);
        short8 b1 = __builtin_bit_cast(short8, *(const uint4*)&Bs[wn * 32 + 16 + lr][kb]);
        acc[0][0] = __builtin_amdgcn_mfma_f32_16x16x32_bf16(a0, b0, acc[0][0], 0, 0, 0);
        acc[0][1] = __builtin_amdgcn_mfma_f32_16x16x32_bf16(a0, b1, acc[0][1], 0, 0, 0);
        acc[1][0] = __builtin_amdgcn_mfma_f32_16x16x32_bf16(a1, b0, acc[1][0], 0, 0, 0);
        acc[1][1] = __builtin_amdgcn_mfma_f32_16x16x32_bf16(a1, b1, acc[1][1], 0, 0, 0);
        __syncthreads();
    }

#pragma unroll
    for (int fm = 0; fm < 2; fm++) {
#pragma unroll
        for (int ri = 0; ri < 4; ri++) {
            int row = gm0 + wm * 32 + fm * 16 + (lane >> 4) * 4 + ri;
            if (row >= M) continue;
#pragma unroll
            for (int fn = 0; fn < 2; fn++) {
                int col = gn0 + wn * 32 + fn * 16 + lr;
                if (col >= N) continue;
                float v = acc[fm][fn][ri];
                if (biasMode == 1)      v += bias[col];
                else if (biasMode == 2) v += bias[row];
                if (doRelu) v = fmaxf(v, 0.f);
                Cg[(long long)row * ldc + col] = v;
            }
        }
    }
}

// ======================= GCN helpers (CSR gather form) =======================
__global__ void count_deg(const int* __restrict__ dst, int E, int* __restrict__ deg)
{
    int i = blockIdx.x * 256 + threadIdx.x;
    if (i < E) atomicAdd(&deg[dst[i]], 1);
}

__global__ void make_dis(const int* __restrict__ deg, float* __restrict__ dis, int n)
{
    int i = blockIdx.x * 256 + threadIdx.x;
    if (i < n) dis[i] = rsqrtf((float)(deg[i] + 1));  // +1 self-loop
}

// exclusive scan of deg[n] -> off[n+1], single block, 256 threads, n % 256 == 0
__global__ __launch_bounds__(256)
void scan_offsets(const int* __restrict__ deg, int* __restrict__ off, int n)
{
    __shared__ int part[256];
    int t = threadIdx.x;
    int chunk = n / 256;
    int s = 0;
    for (int i = 0; i < chunk; i++) s += deg[t * chunk + i];
    part[t] = s;
    __syncthreads();
    if (t == 0) {
        int r = 0;
        for (int j = 0; j < 256; j++) { int x = part[j]; part[j] = r; r += x; }
        off[n] = r;
    }
    __syncthreads();
    int r = part[t];
    for (int i = 0; i < chunk; i++) {
        off[t * chunk + i] = r;
        r += deg[t * chunk + i];
    }
}

// csr[off[d] + slot] = s for each edge (slot via atomic counter; order irrelevant)
__global__ void csr_fill(const int* __restrict__ ei, int E,
                         const int* __restrict__ off, int* __restrict__ cur,
                         int* __restrict__ csr)
{
    int i = blockIdx.x * 256 + threadIdx.x;
    if (i >= E) return;
    int s = ei[i], d = ei[E + i];
    int p = atomicAdd(&cur[d], 1);
    csr[off[d] + p] = s;
}

// fused aggregation: out[v] = dis[v]^2 * h[v] + sum_{s in N(v)} dis[v]*dis[s]*h[s]
// one wave per row, gather form, no atomics
template<int F>
__global__ __launch_bounds__(256)
void agg_gather(const float* __restrict__ tin, const float* __restrict__ dis,
                const int* __restrict__ offs, const int* __restrict__ csr,
                float* __restrict__ out, int n)
{
    constexpr int NS = (F + 63) / 64;
    int v = blockIdx.x * 4 + (threadIdx.x >> 6);
    if (v >= n) return;
    int lane = threadIdx.x & 63;
    float dv = dis[v];
    float acc[NS];
    const float* tv = tin + (size_t)v * F;
#pragma unroll
    for (int k = 0; k < NS; k++) {
        int f = k * 64 + lane;
        acc[k] = (f < F) ? dv * dv * tv[f] : 0.f;
    }
    int o0 = offs[v], o1 = offs[v + 1];
    for (int j = o0; j < o1; j++) {
        int s = csr[j];
        float w = dv * dis[s];
        const float* ts = tin + (size_t)s * F;
#pragma unroll
        for (int k = 0; k < NS; k++) {
            int f = k * 64 + lane;
            if (f < F) acc[k] += w * ts[f];
        }
    }
    float* ov = out + (size_t)v * F;
#pragma unroll
    for (int k = 0; k < NS; k++) {
        int f = k * 64 + lane;
        if (f < F) ov[f] = acc[k];
    }
}

// segment max via uint atomicMax (inputs post-relu >= 0; dst zero-init)
__global__ __launch_bounds__(128)
void pool_max(const float* __restrict__ h, const int* __restrict__ batch,
              float* __restrict__ g, int F)
{
    int v = blockIdx.x;
    int b = batch[v];
    const float* hv = h + (size_t)v * F;
    unsigned int* gu = (unsigned int*)(g + (size_t)b * F);
    for (int f = threadIdx.x; f < F; f += 128)
        atomicMax(&gu[f], __float_as_uint(hv[f]));
}

// ======================= conv branch helpers =======================
__global__ void build_e2(const float* __restrict__ emb, float* __restrict__ e2)
{
    int idx = blockIdx.x * 256 + threadIdx.x;
    if (idx >= 224 * 128) return;
    int kf = idx >> 7, l = idx & 127;
    int v = kf >> 3, k = kf & 7;
    e2[idx] = (v < 26 && (l + k) < 128) ? emb[v * 128 + l + k] : 0.f;
}

__global__ void reorder_w2(const float* __restrict__ w, float* __restrict__ wr)
{
    int idx = blockIdx.x * 256 + threadIdx.x;
    if (idx >= 32 * 2048) return;
    int co = idx >> 11, kf = idx & 2047;
    int k = kf >> 8, ci = kf & 255;
    wr[idx] = w[(co * 256 + ci) * 8 + k];
}

__global__ void reorder_w3(const float* __restrict__ w, float* __restrict__ wr)
{
    int idx = blockIdx.x * 256 + threadIdx.x;
    if (idx >= 32 * 96) return;
    int co = idx / 96, kf = idx % 96;
    int k = kf / 32, ci = kf % 32;
    wr[idx] = w[(co * 32 + ci) * 3 + k];
}

// counting sort of tgt[b] into 26 vocab buckets
__global__ __launch_bounds__(256)
void sort_tgt(const int* __restrict__ tgt, int* __restrict__ perm,
              int* __restrict__ boff)
{
    int b = blockIdx.x;
    __shared__ int tg[SEQ];
    __shared__ int hist[32], cur[32], pre[32];
    int t = threadIdx.x;
    for (int i = t; i < SEQ; i += 256) tg[i] = tgt[b * SEQ + i];
    if (t < 32) hist[t] = 0;
    __syncthreads();
    for (int i = t; i < SEQ; i += 256) atomicAdd(&hist[tg[i]], 1);
    __syncthreads();
    if (t == 0) {
        int s = 0;
        for (int v = 0; v < 29; v++) {
            pre[v] = s; cur[v] = s;
            if (v < 26) s += hist[v];
        }
    }
    __syncthreads();
    for (int i = t; i < SEQ; i += 256) {
        int v = tg[i];
        int p = atomicAdd(&cur[v], 1);
        perm[b * SEQ + p] = i;
    }
    if (t < 29) boff[b * 29 + t] = pre[t];
}

// Wagg[b][co][v*8+k] = sum_{ci in bucket(b,v)} w1[co][ci][k]
// grid (256 co, 4 b-chunks of 128). Block: 4 waves; per round each wave owns one b.
// Lane = (v = lane>>1, k4 = lane&1); accumulates float4 via ds_read_b128.
__global__ __launch_bounds__(256)
void wagg_acc3(const float* __restrict__ w1, const int* __restrict__ perm,
               const int* __restrict__ boff, float* __restrict__ wagg)
{
    int co = blockIdx.x;
    int b0 = blockIdx.y * 128;
    __shared__ __align__(16) float wl[8000];   // w1[co][ci][k]
    __shared__ int pm4[4][1024];
    __shared__ int off4[4][32];
    int t = threadIdx.x;
    for (int i = t; i < 8000; i += 256) wl[i] = w1[(size_t)co * 8000 + i];
    int wv = t >> 6, lane = t & 63;
    int v = lane >> 1, k4 = lane & 1;

    for (int r = 0; r < 32; r++) {
        int bb = b0 + r * 4;
        __syncthreads();   // also covers initial wl staging; guards pm4 reuse
        for (int i = t; i < 4096; i += 256) {
            int slot = i >> 10, idx = i & 1023;
            if (idx < SEQ) pm4[slot][idx] = perm[(bb + slot) * SEQ + idx];
        }
        if (t < 116) {
            int slot = t / 29, j = t % 29;
            off4[slot][j] = boff[(bb + slot) * 29 + j];
        }
        __syncthreads();
        if (v < 28) {
            float4 acc = {0.f, 0.f, 0.f, 0.f};
            int i0 = off4[wv][v], i1 = off4[wv][v + 1];
            for (int i = i0; i < i1; i++) {
                int ci = pm4[wv][i];
                float4 ww = *(const float4*)&wl[ci * 8 + k4 * 4];
                acc.x += ww.x; acc.y += ww.y; acc.z += ww.z; acc.w += ww.w;
            }
            int b = bb + wv;
            *(float4*)&wagg[((size_t)b * 256 + co) * 224 + v * 8 + k4 * 4] = acc;
        }
    }
}

// ======================= head =======================
__global__ __launch_bounds__(256)
void final_dot(const float* __restrict__ z, const float* __restrict__ w,
               const float* __restrict__ ob, float* __restrict__ out)
{
    int b = blockIdx.x;
    float s = 0.f;
    for (int j = threadIdx.x; j < 512; j += 256) s += z[b * 512 + j] * w[j];
    for (int off = 32; off; off >>= 1) s += __shfl_down(s, off, 64);
    __shared__ float red[4];
    if ((threadIdx.x & 63) == 0) red[threadIdx.x >> 6] = s;
    __syncthreads();
    if (threadIdx.x == 0) out[b] = red[0] + red[1] + red[2] + red[3] + ob[0];
}

// ======================= host =======================
extern "C" void kernel_launch(void* const* d_in, const int* in_sizes, int n_in,
                              void* d_out, int out_size, void* d_ws, size_t ws_size,
                              hipStream_t stream)
{
    const float* x      = (const float*)d_in[0];
    const int*   ei     = (const int*)d_in[1];
    const int*   batch  = (const int*)d_in[2];
    const float* cx     = (const float*)d_in[3];
    const int*   cei    = (const int*)d_in[4];
    const int*   cbatch = (const int*)d_in[5];
    const int*   tgt    = (const int*)d_in[6];
    const float* dW1 = (const float*)d_in[7];   const float* db1 = (const float*)d_in[8];
    const float* dW2 = (const float*)d_in[9];   const float* db2 = (const float*)d_in[10];
    const float* dW3 = (const float*)d_in[11];  const float* db3 = (const float*)d_in[12];
    const float* fcg1W = (const float*)d_in[13]; const float* fcg1b = (const float*)d_in[14];
    const float* fcg2W = (const float*)d_in[15]; const float* fcg2b = (const float*)d_in[16];
    const float* cW1 = (const float*)d_in[17];  const float* cb1 = (const float*)d_in[18];
    const float* cW2 = (const float*)d_in[19];  const float* cb2 = (const float*)d_in[20];
    const float* cW3 = (const float*)d_in[21];  const float* cb3 = (const float*)d_in[22];
    const float* cg1W = (const float*)d_in[23]; const float* cg1b = (const float*)d_in[24];
    const float* cg2W = (const float*)d_in[25]; const float* cg2b = (const float*)d_in[26];
    const float* emb  = (const float*)d_in[27];
    const float* cx1W = (const float*)d_in[28]; const float* cx1b = (const float*)d_in[29];
    const float* cx2W = (const float*)d_in[30]; const float* cx2b = (const float*)d_in[31];
    const float* cx3W = (const float*)d_in[32]; const float* cx3b = (const float*)d_in[33];
    const float* fxtW = (const float*)d_in[34]; const float* fxtb = (const float*)d_in[35];
    const float* f1W  = (const float*)d_in[36]; const float* f1b  = (const float*)d_in[37];
    const float* f2W  = (const float*)d_in[38]; const float* f2b  = (const float*)d_in[39];
    const float* oW   = (const float*)d_in[40]; const float* ob   = (const float*)d_in[41];

    char* w8 = (char*)d_ws;
    // GCN phase: bufA (agg out, F<=202) 0..52,953,088; bufB (gemm out, F<=404) ..158,859,264
    float* bufA = (float*)(w8);
    float* bufB = (float*)(w8 + 52953088);
    // CSR arrays (GCN phase only; conv c1 region overlaps them later, stream-ordered safe)
    // SIZES: off_a 65537*4=262,148 | cur_a 262,144 | csr_a 1,048,576
    //        off_c 32769*4=131,076 | cur_c 131,072 | csr_c   524,288
    int*   off_a = (int*)(w8 + 160000000);           // ..160,262,148
    int*   cur_a = (int*)(w8 + 160262400);           // ..160,524,544
    int*   csr_a = (int*)(w8 + 160524544);           // ..161,573,120
    int*   off_c = (int*)(w8 + 161573120);           // ..161,704,196  (33769th int included!)
    int*   cur_c = (int*)(w8 + 161704448);           // ..161,835,520
    int*   csr_c = (int*)(w8 + 161835520);           // ..162,359,808
    // conv phase (after GCN done): Wagg at 0, c1/c2/c3 behind it
    float* Wagg = (float*)(w8);                      // 512*256*224*4 = 117,440,512
    float* c1   = (float*)(w8 + 117440512);          // 512*256*128*4 = 67,108,864
    float* c2   = (float*)(w8 + 184549376);          // 512*32*128*4  =  8,388,608
    float* c3   = (float*)(w8 + 192937984);          // 512*112*32*4  =  7,340,032
    int*   perm = (int*)(w8 + 200279040);            // 512*1000*4 (sort_tgt .. wagg_acc3)
    int*   boff = (int*)(w8 + 202327296);            // 512*29*4
    size_t off  = 211812352;
    auto take = [&](size_t bytes) -> void* {
        void* p = w8 + off;
        off += (bytes + 255) & ~(size_t)255;
        return p;
    };
    float* g0  = (float*)take(512 * 404 * 4);
    float* q0  = (float*)take(512 * 140 * 4);
    float* gh  = (float*)take(512 * 1024 * 4);
    float* qh  = (float*)take(512 * 1024 * 4);
    float* zc  = (float*)take(512 * 384 * 4);
    float* zc1 = (float*)take(512 * 1024 * 4);
    float* zc2 = (float*)take(512 * 512 * 4);
    int*   dega = (int*)take(N_ATOM * 4);
    float* disa = (float*)take(N_ATOM * 4);
    int*   degc = (int*)take(N_CLQ * 4);
    float* disc = (float*)take(N_CLQ * 4);
    float* E2   = (float*)take(224 * 128 * 4);
    float* w2r  = (float*)take(32 * 2048 * 4);
    float* w3r  = (float*)take(32 * 96 * 4);
    float* outp = (float*)d_out;

    auto gemm = [&](int policy, const float* A, const float* B, float* C,
                    const float* bias, int M, int N, int K,
                    int lda, int ldb, int ldc,
                    long long sA, long long sB, long long sC, int G,
                    int biasMode, int relu, int cmask, int cshift) {
        dim3 grid((N + 63) / 64, (M + 63) / 64, G);
        if (policy == 0)
            hipLaunchKernelGGL((gemm_mf<0>), grid, dim3(256), 0, stream,
                A, B, C, bias, M, N, K, lda, ldb, ldc, sA, sB, sC, biasMode, relu, cmask, cshift);
        else
            hipLaunchKernelGGL((gemm_mf<1>), grid, dim3(256), 0, stream,
                A, B, C, bias, M, N, K, lda, ldb, ldc, sA, sB, sC, biasMode, relu, cmask, cshift);
    };

    // ---------- init ----------
    hipMemsetAsync(dega, 0, N_ATOM * 4, stream);
    hipMemsetAsync(degc, 0, N_CLQ * 4, stream);
    hipMemsetAsync(cur_a, 0, N_ATOM * 4, stream);
    hipMemsetAsync(cur_c, 0, N_CLQ * 4, stream);
    hipMemsetAsync(g0, 0, 512 * 404 * 4, stream);
    hipMemsetAsync(q0, 0, 512 * 140 * 4, stream);

    // ---------- CSR build (atoms + cliques) ----------
    count_deg<<<(E_ATOM + 255) / 256, 256, 0, stream>>>(ei + E_ATOM, E_ATOM, dega);
    make_dis<<<(N_ATOM + 255) / 256, 256, 0, stream>>>(dega, disa, N_ATOM);
    scan_offsets<<<1, 256, 0, stream>>>(dega, off_a, N_ATOM);
    csr_fill<<<(E_ATOM + 255) / 256, 256, 0, stream>>>(ei, E_ATOM, off_a, cur_a, csr_a);

    count_deg<<<(E_CLQ + 255) / 256, 256, 0, stream>>>(cei + E_CLQ, E_CLQ, degc);
    make_dis<<<(N_CLQ + 255) / 256, 256, 0, stream>>>(degc, disc, N_CLQ);
    scan_offsets<<<1, 256, 0, stream>>>(degc, off_c, N_CLQ);
    csr_fill<<<(E_CLQ + 255) / 256, 256, 0, stream>>>(cei, E_CLQ, off_c, cur_c, csr_c);

    // ---------- atom GCN branch (gather agg at F_in, bias+relu fused into GEMM) ----------
    agg_gather<101><<<N_ATOM / 4, 256, 0, stream>>>(x, disa, off_a, csr_a, bufA, N_ATOM);
    gemm(0, bufA, dW1, bufB, db1, N_ATOM, 101, 101, 101, 101, 101, 0, 0, 0, 1, 1, 1, 0, 0);

    agg_gather<101><<<N_ATOM / 4, 256, 0, stream>>>(bufB, disa, off_a, csr_a, bufA, N_ATOM);
    gemm(0, bufA, dW2, bufB, db2, N_ATOM, 202, 101, 101, 202, 202, 0, 0, 0, 1, 1, 1, 0, 0);

    agg_gather<202><<<N_ATOM / 4, 256, 0, stream>>>(bufB, disa, off_a, csr_a, bufA, N_ATOM);
    gemm(0, bufA, dW3, bufB, db3, N_ATOM, 404, 202, 202, 404, 404, 0, 0, 0, 1, 1, 1, 0, 0);

    pool_max<<<N_ATOM, 128, 0, stream>>>(bufB, batch, g0, 404);
    gemm(0, g0, fcg1W, gh, fcg1b, 512, 1024, 404, 404, 1024, 1024, 0, 0, 0, 1, 1, 1, 0, 0);
    gemm(0, gh, fcg2W, zc + 0, fcg2b, 512, 128, 1024, 1024, 128, 384, 0, 0, 0, 1, 1, 0, 0, 0);

    // ---------- clique GCN branch ----------
    agg_gather<35><<<N_CLQ / 4, 256, 0, stream>>>(cx, disc, off_c, csr_c, bufA, N_CLQ);
    gemm(0, bufA, cW1, bufB, cb1, N_CLQ, 35, 35, 35, 35, 35, 0, 0, 0, 1, 1, 1, 0, 0);

    agg_gather<35><<<N_CLQ / 4, 256, 0, stream>>>(bufB, disc, off_c, csr_c, bufA, N_CLQ);
    gemm(0, bufA, cW2, bufB, cb2, N_CLQ, 70, 35, 35, 70, 70, 0, 0, 0, 1, 1, 1, 0, 0);

    agg_gather<70><<<N_CLQ / 4, 256, 0, stream>>>(bufB, disc, off_c, csr_c, bufA, N_CLQ);
    gemm(0, bufA, cW3, bufB, cb3, N_CLQ, 140, 70, 70, 140, 140, 0, 0, 0, 1, 1, 1, 0, 0);

    pool_max<<<N_CLQ, 128, 0, stream>>>(bufB, cbatch, q0, 140);
    gemm(0, q0, cg1W, qh, cg1b, 512, 1024, 140, 140, 1024, 1024, 0, 0, 0, 1, 1, 1, 0, 0);
    gemm(0, qh, cg2W, zc + 256, cg2b, 512, 128, 1024, 1024, 128, 384, 0, 0, 0, 1, 1, 0, 0, 0);

    // ---------- protein conv branch (vocab-factorized conv1) ----------
    sort_tgt<<<512, 256, 0, stream>>>(tgt, perm, boff);
    build_e2<<<(224 * 128 + 255) / 256, 256, 0, stream>>>(emb, E2);
    reorder_w2<<<(32 * 2048 + 255) / 256, 256, 0, stream>>>(cx2W, w2r);
    reorder_w3<<<(32 * 96 + 255) / 256, 256, 0, stream>>>(cx3W, w3r);
    wagg_acc3<<<dim3(256, 4), 256, 0, stream>>>(cx1W, perm, boff, Wagg);

    // conv1: c1[b] (256x121) = Wagg[b] (256x224) @ E2 (224x128), bias per row
    gemm(0, Wagg, E2, c1, cx1b, 256, 121, 224, 224, 128, 128,
         57344LL, 0LL, 32768LL, 512, 2, 0, 0, 0);
    // conv2: c2[b] (32x114) = w2r (32x2048) @ im2col(c1[b]),  k = kk*256+ci
    gemm(1, w2r, c1, c2, cx2b, 32, 114, 2048, 2048, 128, 128,
         0LL, 32768LL, 4096LL, 512, 2, 0, 255, 8);
    // conv3: c3[b] (32x112) = w3r (32x96) @ im2col(c2[b]),    k = kk*32+ci
    gemm(1, w3r, c2, c3, cx3b, 32, 112, 96, 96, 128, 112,
         0LL, 4096LL, 3584LL, 512, 2, 0, 31, 5);
    // xt = c3 (512x3584) @ fxtW -> zc cols 128..255
    gemm(0, c3, fxtW, zc + 128, fxtb, 512, 128, 3584, 3584, 128, 384,
         0, 0, 0, 1, 1, 0, 0, 0);

    // ---------- head ----------
    gemm(0, zc, f1W, zc1, f1b, 512, 1024, 384, 384, 1024, 1024, 0, 0, 0, 1, 1, 1, 0, 0);
    gemm(0, zc1, f2W, zc2, f2b, 512, 512, 1024, 1024, 512, 512, 0, 0, 0, 1, 1, 1, 0, 0);
    final_dot<<<512, 256, 0, stream>>>(zc2, oW, ob, outp);
}

// Round 6
// 2283.236 us; speedup vs baseline: 1.9063x; 1.0730x over previous
//
#include <hip/hip_runtime.h>
#include <cstdint>
#include <cstddef>

#define N_ATOM 65536
#define E_ATOM 262144
#define N_CLQ  32768
#define E_CLQ  131072
#define BSZ    512
#define SEQ    1000

typedef __attribute__((ext_vector_type(8))) short short8;
typedef __attribute__((ext_vector_type(4))) float f32x4;

__device__ __forceinline__ unsigned short f2bf(float x) {
    unsigned int u = __float_as_uint(x);
    u += 0x7FFFu + ((u >> 16) & 1u);          // round-to-nearest-even
    return (unsigned short)(u >> 16);
}

// ======================= bf16 MFMA GEMM =======================
// C[g] = A[g] (MxK fp32 row-major) @ B[g] (KxN fp32) + bias, optional relu.
// POLICY 0: B[k][n] = Bg[k*ldb + n]
// POLICY 1: B[k][n] = Bg[(k & cmask)*ldb + n + (k >> cshift)]  (conv im2col view)
// Block: 256 thr = 4 waves (2x2), wave tile 32x32 (2x2 mfma 16x16x32), block tile 64x64.
template<int POLICY>
__global__ __launch_bounds__(256)
void gemm_mf(const float* __restrict__ A, const float* __restrict__ B,
             float* __restrict__ C, const float* __restrict__ bias,
             int M, int N, int K, int lda, int ldb, int ldc,
             long long sA, long long sB, long long sC,
             int biasMode, int doRelu, int cmask, int cshift)
{
    __shared__ __align__(16) unsigned short As[64][40];  // [m][k] pad 40 (80B rows)
    __shared__ __align__(16) unsigned short Bs[64][40];  // [n][k] (transposed in)
    const int g = blockIdx.z;
    const float* __restrict__ Ag = A + (long long)g * sA;
    const float* __restrict__ Bg = B + (long long)g * sB;
    float* __restrict__ Cg = C + (long long)g * sC;
    const int gm0 = blockIdx.y * 64, gn0 = blockIdx.x * 64;
    const int t = threadIdx.x;
    const int lane = t & 63, wv = t >> 6, wm = wv >> 1, wn = wv & 1;
    const int lr = lane & 15, kb = (lane >> 4) * 8;
    const int am = t >> 2,  ak = (t & 3) * 8;    // A stager: row am, 8 k's at ak
    const int bn = t & 63,  bk = (t >> 6) * 8;   // B stager: col bn, 8 k's at bk

    f32x4 acc[2][2] = {};

    for (int k0 = 0; k0 < K; k0 += 32) {
        { // stage A tile (fp32 -> bf16)
            int gm = gm0 + am;
            unsigned int p[4];
#pragma unroll
            for (int j2 = 0; j2 < 4; j2++) {
                float v0 = 0.f, v1 = 0.f;
                int gk0 = k0 + ak + j2 * 2, gk1 = gk0 + 1;
                if (gm < M) {
                    if (gk0 < K) v0 = Ag[(long long)gm * lda + gk0];
                    if (gk1 < K) v1 = Ag[(long long)gm * lda + gk1];
                }
                p[j2] = (unsigned int)f2bf(v0) | ((unsigned int)f2bf(v1) << 16);
            }
            *(uint4*)&As[am][ak] = make_uint4(p[0], p[1], p[2], p[3]);
        }
        { // stage B tile transposed (fp32 -> bf16), coalesced along n
            int gn = gn0 + bn;
            unsigned int p[4];
#pragma unroll
            for (int j2 = 0; j2 < 4; j2++) {
                float v0 = 0.f, v1 = 0.f;
                int gk0 = k0 + bk + j2 * 2, gk1 = gk0 + 1;
                if (gn < N) {
                    if (gk0 < K)
                        v0 = (POLICY == 0) ? Bg[(long long)gk0 * ldb + gn]
                                           : Bg[(long long)(gk0 & cmask) * ldb + gn + (gk0 >> cshift)];
                    if (gk1 < K)
                        v1 = (POLICY == 0) ? Bg[(long long)gk1 * ldb + gn]
                                           : Bg[(long long)(gk1 & cmask) * ldb + gn + (gk1 >> cshift)];
                }
                p[j2] = (unsigned int)f2bf(v0) | ((unsigned int)f2bf(v1) << 16);
            }
            *(uint4*)&Bs[bn][bk] = make_uint4(p[0], p[1], p[2], p[3]);
        }
        __syncthreads();
        short8 a0 = __builtin_bit_cast(short8, *(const uint4*)&As[wm * 32 + lr][kb]);
        short8 a1 = __builtin_bit_cast(short8, *(const uint4*)&As[wm * 32 + 16 + lr][kb]);
        short8 b0 = __builtin_bit_cast(short8, *(const uint4*)&Bs[wn * 32 + lr][kb]);
        short8 b1 = __builtin_bit_cast(short8, *(const uint4*)&Bs[wn * 32 + 16 + lr][kb]);
        acc[0][0] = __builtin_amdgcn_mfma_f32_16x16x32_bf16(a0, b0, acc[0][0], 0, 0, 0);
        acc[0][1] = __builtin_amdgcn_mfma_f32_16x16x32_bf16(a0, b1, acc[0][1], 0, 0, 0);
        acc[1][0] = __builtin_amdgcn_mfma_f32_16x16x32_bf16(a1, b0, acc[1][0], 0, 0, 0);
        acc[1][1] = __builtin_amdgcn_mfma_f32_16x16x32_bf16(a1, b1, acc[1][1], 0, 0, 0);
        __syncthreads();
    }

#pragma unroll
    for (int fm = 0; fm < 2; fm++) {
#pragma unroll
        for (int ri = 0; ri < 4; ri++) {
            int row = gm0 + wm * 32 + fm * 16 + (lane >> 4) * 4 + ri;
            if (row >= M) continue;
#pragma unroll
            for (int fn = 0; fn < 2; fn++) {
                int col = gn0 + wn * 32 + fn * 16 + lr;
                if (col >= N) continue;
                float v = acc[fm][fn][ri];
                if (biasMode == 1)      v += bias[col];
                else if (biasMode == 2) v += bias[row];
                if (doRelu) v = fmaxf(v, 0.f);
                Cg[(long long)row * ldc + col] = v;
            }
        }
    }
}

// ======================= GCN helpers (CSR gather form) =======================
__global__ void count_deg(const int* __restrict__ dst, int E, int* __restrict__ deg)
{
    int i = blockIdx.x * 256 + threadIdx.x;
    if (i < E) atomicAdd(&deg[dst[i]], 1);
}

__global__ void make_dis(const int* __restrict__ deg, float* __restrict__ dis, int n)
{
    int i = blockIdx.x * 256 + threadIdx.x;
    if (i < n) dis[i] = rsqrtf((float)(deg[i] + 1));  // +1 self-loop
}

// exclusive scan of deg[n] -> off[n+1], single block, 256 threads, n % 256 == 0
__global__ __launch_bounds__(256)
void scan_offsets(const int* __restrict__ deg, int* __restrict__ off, int n)
{
    __shared__ int part[256];
    int t = threadIdx.x;
    int chunk = n / 256;
    int s = 0;
    for (int i = 0; i < chunk; i++) s += deg[t * chunk + i];
    part[t] = s;
    __syncthreads();
    if (t == 0) {
        int r = 0;
        for (int j = 0; j < 256; j++) { int x = part[j]; part[j] = r; r += x; }
        off[n] = r;
    }
    __syncthreads();
    int r = part[t];
    for (int i = 0; i < chunk; i++) {
        off[t * chunk + i] = r;
        r += deg[t * chunk + i];
    }
}

// csr[off[d] + slot] = s for each edge (slot via atomic counter; order irrelevant)
__global__ void csr_fill(const int* __restrict__ ei, int E,
                         const int* __restrict__ off, int* __restrict__ cur,
                         int* __restrict__ csr)
{
    int i = blockIdx.x * 256 + threadIdx.x;
    if (i >= E) return;
    int s = ei[i], d = ei[E + i];
    int p = atomicAdd(&cur[d], 1);
    csr[off[d] + p] = s;
}

// fused aggregation: out[v] = dis[v]^2 * h[v] + sum_{s in N(v)} dis[v]*dis[s]*h[s]
// one wave per row, gather form, no atomics
template<int F>
__global__ __launch_bounds__(256)
void agg_gather(const float* __restrict__ tin, const float* __restrict__ dis,
                const int* __restrict__ offs, const int* __restrict__ csr,
                float* __restrict__ out, int n)
{
    constexpr int NS = (F + 63) / 64;
    int v = blockIdx.x * 4 + (threadIdx.x >> 6);
    if (v >= n) return;
    int lane = threadIdx.x & 63;
    float dv = dis[v];
    float acc[NS];
    const float* tv = tin + (size_t)v * F;
#pragma unroll
    for (int k = 0; k < NS; k++) {
        int f = k * 64 + lane;
        acc[k] = (f < F) ? dv * dv * tv[f] : 0.f;
    }
    int o0 = offs[v], o1 = offs[v + 1];
    for (int j = o0; j < o1; j++) {
        int s = csr[j];
        float w = dv * dis[s];
        const float* ts = tin + (size_t)s * F;
#pragma unroll
        for (int k = 0; k < NS; k++) {
            int f = k * 64 + lane;
            if (f < F) acc[k] += w * ts[f];
        }
    }
    float* ov = out + (size_t)v * F;
#pragma unroll
    for (int k = 0; k < NS; k++) {
        int f = k * 64 + lane;
        if (f < F) ov[f] = acc[k];
    }
}

// segment max via uint atomicMax (inputs post-relu >= 0; dst zero-init)
__global__ __launch_bounds__(128)
void pool_max(const float* __restrict__ h, const int* __restrict__ batch,
              float* __restrict__ g, int F)
{
    int v = blockIdx.x;
    int b = batch[v];
    const float* hv = h + (size_t)v * F;
    unsigned int* gu = (unsigned int*)(g + (size_t)b * F);
    for (int f = threadIdx.x; f < F; f += 128)
        atomicMax(&gu[f], __float_as_uint(hv[f]));
}

// ======================= conv branch helpers =======================
__global__ void build_e2(const float* __restrict__ emb, float* __restrict__ e2)
{
    int idx = blockIdx.x * 256 + threadIdx.x;
    if (idx >= 224 * 128) return;
    int kf = idx >> 7, l = idx & 127;
    int v = kf >> 3, k = kf & 7;
    e2[idx] = (v < 26 && (l + k) < 128) ? emb[v * 128 + l + k] : 0.f;
}

__global__ void reorder_w2(const float* __restrict__ w, float* __restrict__ wr)
{
    int idx = blockIdx.x * 256 + threadIdx.x;
    if (idx >= 32 * 2048) return;
    int co = idx >> 11, kf = idx & 2047;
    int k = kf >> 8, ci = kf & 255;
    wr[idx] = w[(co * 256 + ci) * 8 + k];
}

__global__ void reorder_w3(const float* __restrict__ w, float* __restrict__ wr)
{
    int idx = blockIdx.x * 256 + threadIdx.x;
    if (idx >= 32 * 96) return;
    int co = idx / 96, kf = idx % 96;
    int k = kf / 32, ci = kf % 32;
    wr[idx] = w[(co * 32 + ci) * 3 + k];
}

// counting sort of tgt[b] into 26 vocab buckets
__global__ __launch_bounds__(256)
void sort_tgt(const int* __restrict__ tgt, int* __restrict__ perm,
              int* __restrict__ boff)
{
    int b = blockIdx.x;
    __shared__ int tg[SEQ];
    __shared__ int hist[32], cur[32], pre[32];
    int t = threadIdx.x;
    for (int i = t; i < SEQ; i += 256) tg[i] = tgt[b * SEQ + i];
    if (t < 32) hist[t] = 0;
    __syncthreads();
    for (int i = t; i < SEQ; i += 256) atomicAdd(&hist[tg[i]], 1);
    __syncthreads();
    if (t == 0) {
        int s = 0;
        for (int v = 0; v < 29; v++) {
            pre[v] = s; cur[v] = s;
            if (v < 26) s += hist[v];
        }
    }
    __syncthreads();
    for (int i = t; i < SEQ; i += 256) {
        int v = tg[i];
        int p = atomicAdd(&cur[v], 1);
        perm[b * SEQ + p] = i;
    }
    if (t < 29) boff[b * 29 + t] = pre[t];
}

// Wagg[b][co][v*8+k] = sum_{ci in bucket(b,v)} w1[co][ci][k]
// grid (256 co, 8 b-chunks of 64), block 256 = 4 waves; per round each wave owns one b.
// w1[co] staged in LDS as PACKED bf16 pairs: wl16[ci*4+k2] = bf(w[2k2]) | bf(w[2k2+1])<<16.
// Lane (j = lane>>2 -> v = g*16+j, k2 = lane&3): b32 reads, ~4-way max bank spread,
// no cross-lane reduction (each lane owns its whole bucket for its k-pair).
__global__ __launch_bounds__(256)
void wagg_acc4(const float* __restrict__ w1, const int* __restrict__ perm,
               const int* __restrict__ boff, float* __restrict__ wagg)
{
    int co = blockIdx.x;
    int b0 = blockIdx.y * 64;
    __shared__ unsigned int wl16[4000];
    __shared__ int pm4[4][1000];
    __shared__ int off4[4][32];
    int t = threadIdx.x;
    for (int i = t; i < 4000; i += 256) {
        float2 w2 = *(const float2*)&w1[(size_t)co * 8000 + (size_t)i * 2];
        wl16[i] = (unsigned int)f2bf(w2.x) | ((unsigned int)f2bf(w2.y) << 16);
    }
    int wv = t >> 6, lane = t & 63;
    int j = lane >> 2, k2 = lane & 3;

    for (int r = 0; r < 16; r++) {
        int bb = b0 + r * 4;
        __syncthreads();   // covers wl16 staging on r=0; guards pm4 reuse after
        for (int i = t; i < 4096; i += 256) {
            int slot = i >> 10, idx = i & 1023;
            if (idx < SEQ) pm4[slot][idx] = perm[(bb + slot) * SEQ + idx];
        }
        if (t < 116) {
            int slot = t / 29, jj = t % 29;
            off4[slot][jj] = boff[(bb + slot) * 29 + jj];
        }
        __syncthreads();
        int b = bb + wv;
        float* op = &wagg[((size_t)b * 256 + co) * 224];
#pragma unroll
        for (int g = 0; g < 2; g++) {
            int v = g * 16 + j;
            if (v < 28) {
                float a0 = 0.f, a1 = 0.f;
                int i1 = off4[wv][v + 1];
                for (int i = off4[wv][v]; i < i1; i++) {
                    unsigned int u = wl16[pm4[wv][i] * 4 + k2];
                    a0 += __uint_as_float(u << 16);
                    a1 += __uint_as_float(u & 0xffff0000u);
                }
                *(float2*)&op[v * 8 + k2 * 2] = make_float2(a0, a1);
            }
        }
    }
}

// ======================= head =======================
__global__ __launch_bounds__(256)
void final_dot(const float* __restrict__ z, const float* __restrict__ w,
               const float* __restrict__ ob, float* __restrict__ out)
{
    int b = blockIdx.x;
    float s = 0.f;
    for (int j = threadIdx.x; j < 512; j += 256) s += z[b * 512 + j] * w[j];
    for (int off = 32; off; off >>= 1) s += __shfl_down(s, off, 64);
    __shared__ float red[4];
    if ((threadIdx.x & 63) == 0) red[threadIdx.x >> 6] = s;
    __syncthreads();
    if (threadIdx.x == 0) out[b] = red[0] + red[1] + red[2] + red[3] + ob[0];
}

// ======================= host =======================
extern "C" void kernel_launch(void* const* d_in, const int* in_sizes, int n_in,
                              void* d_out, int out_size, void* d_ws, size_t ws_size,
                              hipStream_t stream)
{
    const float* x      = (const float*)d_in[0];
    const int*   ei     = (const int*)d_in[1];
    const int*   batch  = (const int*)d_in[2];
    const float* cx     = (const float*)d_in[3];
    const int*   cei    = (const int*)d_in[4];
    const int*   cbatch = (const int*)d_in[5];
    const int*   tgt    = (const int*)d_in[6];
    const float* dW1 = (const float*)d_in[7];   const float* db1 = (const float*)d_in[8];
    const float* dW2 = (const float*)d_in[9];   const float* db2 = (const float*)d_in[10];
    const float* dW3 = (const float*)d_in[11];  const float* db3 = (const float*)d_in[12];
    const float* fcg1W = (const float*)d_in[13]; const float* fcg1b = (const float*)d_in[14];
    const float* fcg2W = (const float*)d_in[15]; const float* fcg2b = (const float*)d_in[16];
    const float* cW1 = (const float*)d_in[17];  const float* cb1 = (const float*)d_in[18];
    const float* cW2 = (const float*)d_in[19];  const float* cb2 = (const float*)d_in[20];
    const float* cW3 = (const float*)d_in[21];  const float* cb3 = (const float*)d_in[22];
    const float* cg1W = (const float*)d_in[23]; const float* cg1b = (const float*)d_in[24];
    const float* cg2W = (const float*)d_in[25]; const float* cg2b = (const float*)d_in[26];
    const float* emb  = (const float*)d_in[27];
    const float* cx1W = (const float*)d_in[28]; const float* cx1b = (const float*)d_in[29];
    const float* cx2W = (const float*)d_in[30]; const float* cx2b = (const float*)d_in[31];
    const float* cx3W = (const float*)d_in[32]; const float* cx3b = (const float*)d_in[33];
    const float* fxtW = (const float*)d_in[34]; const float* fxtb = (const float*)d_in[35];
    const float* f1W  = (const float*)d_in[36]; const float* f1b  = (const float*)d_in[37];
    const float* f2W  = (const float*)d_in[38]; const float* f2b  = (const float*)d_in[39];
    const float* oW   = (const float*)d_in[40]; const float* ob   = (const float*)d_in[41];

    char* w8 = (char*)d_ws;
    // GCN phase: bufA (agg out, F<=202) 0..52,953,088; bufB (gemm out, F<=404) ..158,859,264
    float* bufA = (float*)(w8);
    float* bufB = (float*)(w8 + 52953088);
    // CSR arrays (GCN phase only; conv c1 region overlaps them later, stream-ordered safe)
    // SIZES: off_a 65537*4=262,148 | cur_a 262,144 | csr_a 1,048,576
    //        off_c 32769*4=131,076 | cur_c 131,072 | csr_c   524,288
    int*   off_a = (int*)(w8 + 160000000);           // ..160,262,148
    int*   cur_a = (int*)(w8 + 160262400);           // ..160,524,544
    int*   csr_a = (int*)(w8 + 160524544);           // ..161,573,120
    int*   off_c = (int*)(w8 + 161573120);           // ..161,704,196  (32769th int included)
    int*   cur_c = (int*)(w8 + 161704448);           // ..161,835,520
    int*   csr_c = (int*)(w8 + 161835520);           // ..162,359,808
    // conv phase (after GCN done): Wagg at 0, c1/c2/c3 behind it
    float* Wagg = (float*)(w8);                      // 512*256*224*4 = 117,440,512
    float* c1   = (float*)(w8 + 117440512);          // 512*256*128*4 = 67,108,864
    float* c2   = (float*)(w8 + 184549376);          // 512*32*128*4  =  8,388,608
    float* c3   = (float*)(w8 + 192937984);          // 512*112*32*4  =  7,340,032
    int*   perm = (int*)(w8 + 200279040);            // 512*1000*4 (sort_tgt .. wagg_acc4)
    int*   boff = (int*)(w8 + 202327296);            // 512*29*4
    size_t off  = 211812352;
    auto take = [&](size_t bytes) -> void* {
        void* p = w8 + off;
        off += (bytes + 255) & ~(size_t)255;
        return p;
    };
    float* g0  = (float*)take(512 * 404 * 4);
    float* q0  = (float*)take(512 * 140 * 4);
    float* gh  = (float*)take(512 * 1024 * 4);
    float* qh  = (float*)take(512 * 1024 * 4);
    float* zc  = (float*)take(512 * 384 * 4);
    float* zc1 = (float*)take(512 * 1024 * 4);
    float* zc2 = (float*)take(512 * 512 * 4);
    int*   dega = (int*)take(N_ATOM * 4);
    float* disa = (float*)take(N_ATOM * 4);
    int*   degc = (int*)take(N_CLQ * 4);
    float* disc = (float*)take(N_CLQ * 4);
    float* E2   = (float*)take(224 * 128 * 4);
    float* w2r  = (float*)take(32 * 2048 * 4);
    float* w3r  = (float*)take(32 * 96 * 4);
    float* outp = (float*)d_out;

    auto gemm = [&](int policy, const float* A, const float* B, float* C,
                    const float* bias, int M, int N, int K,
                    int lda, int ldb, int ldc,
                    long long sA, long long sB, long long sC, int G,
                    int biasMode, int relu, int cmask, int cshift) {
        dim3 grid((N + 63) / 64, (M + 63) / 64, G);
        if (policy == 0)
            hipLaunchKernelGGL((gemm_mf<0>), grid, dim3(256), 0, stream,
                A, B, C, bias, M, N, K, lda, ldb, ldc, sA, sB, sC, biasMode, relu, cmask, cshift);
        else
            hipLaunchKernelGGL((gemm_mf<1>), grid, dim3(256), 0, stream,
                A, B, C, bias, M, N, K, lda, ldb, ldc, sA, sB, sC, biasMode, relu, cmask, cshift);
    };

    // ---------- init ----------
    hipMemsetAsync(dega, 0, N_ATOM * 4, stream);
    hipMemsetAsync(degc, 0, N_CLQ * 4, stream);
    hipMemsetAsync(cur_a, 0, N_ATOM * 4, stream);
    hipMemsetAsync(cur_c, 0, N_CLQ * 4, stream);
    hipMemsetAsync(g0, 0, 512 * 404 * 4, stream);
    hipMemsetAsync(q0, 0, 512 * 140 * 4, stream);

    // ---------- CSR build (atoms + cliques) ----------
    count_deg<<<(E_ATOM + 255) / 256, 256, 0, stream>>>(ei + E_ATOM, E_ATOM, dega);
    make_dis<<<(N_ATOM + 255) / 256, 256, 0, stream>>>(dega, disa, N_ATOM);
    scan_offsets<<<1, 256, 0, stream>>>(dega, off_a, N_ATOM);
    csr_fill<<<(E_ATOM + 255) / 256, 256, 0, stream>>>(ei, E_ATOM, off_a, cur_a, csr_a);

    count_deg<<<(E_CLQ + 255) / 256, 256, 0, stream>>>(cei + E_CLQ, E_CLQ, degc);
    make_dis<<<(N_CLQ + 255) / 256, 256, 0, stream>>>(degc, disc, N_CLQ);
    scan_offsets<<<1, 256, 0, stream>>>(degc, off_c, N_CLQ);
    csr_fill<<<(E_CLQ + 255) / 256, 256, 0, stream>>>(cei, E_CLQ, off_c, cur_c, csr_c);

    // ---------- atom GCN branch (gather agg at F_in, bias+relu fused into GEMM) ----------
    agg_gather<101><<<N_ATOM / 4, 256, 0, stream>>>(x, disa, off_a, csr_a, bufA, N_ATOM);
    gemm(0, bufA, dW1, bufB, db1, N_ATOM, 101, 101, 101, 101, 101, 0, 0, 0, 1, 1, 1, 0, 0);

    agg_gather<101><<<N_ATOM / 4, 256, 0, stream>>>(bufB, disa, off_a, csr_a, bufA, N_ATOM);
    gemm(0, bufA, dW2, bufB, db2, N_ATOM, 202, 101, 101, 202, 202, 0, 0, 0, 1, 1, 1, 0, 0);

    agg_gather<202><<<N_ATOM / 4, 256, 0, stream>>>(bufB, disa, off_a, csr_a, bufA, N_ATOM);
    gemm(0, bufA, dW3, bufB, db3, N_ATOM, 404, 202, 202, 404, 404, 0, 0, 0, 1, 1, 1, 0, 0);

    pool_max<<<N_ATOM, 128, 0, stream>>>(bufB, batch, g0, 404);
    gemm(0, g0, fcg1W, gh, fcg1b, 512, 1024, 404, 404, 1024, 1024, 0, 0, 0, 1, 1, 1, 0, 0);
    gemm(0, gh, fcg2W, zc + 0, fcg2b, 512, 128, 1024, 1024, 128, 384, 0, 0, 0, 1, 1, 0, 0, 0);

    // ---------- clique GCN branch ----------
    agg_gather<35><<<N_CLQ / 4, 256, 0, stream>>>(cx, disc, off_c, csr_c, bufA, N_CLQ);
    gemm(0, bufA, cW1, bufB, cb1, N_CLQ, 35, 35, 35, 35, 35, 0, 0, 0, 1, 1, 1, 0, 0);

    agg_gather<35><<<N_CLQ / 4, 256, 0, stream>>>(bufB, disc, off_c, csr_c, bufA, N_CLQ);
    gemm(0, bufA, cW2, bufB, cb2, N_CLQ, 70, 35, 35, 70, 70, 0, 0, 0, 1, 1, 1, 0, 0);

    agg_gather<70><<<N_CLQ / 4, 256, 0, stream>>>(bufB, disc, off_c, csr_c, bufA, N_CLQ);
    gemm(0, bufA, cW3, bufB, cb3, N_CLQ, 140, 70, 70, 140, 140, 0, 0, 0, 1, 1, 1, 0, 0);

    pool_max<<<N_CLQ, 128, 0, stream>>>(bufB, cbatch, q0, 140);
    gemm(0, q0, cg1W, qh, cg1b, 512, 1024, 140, 140, 1024, 1024, 0, 0, 0, 1, 1, 1, 0, 0);
    gemm(0, qh, cg2W, zc + 256, cg2b, 512, 128, 1024, 1024, 128, 384, 0, 0, 0, 1, 1, 0, 0, 0);

    // ---------- protein conv branch (vocab-factorized conv1) ----------
    sort_tgt<<<512, 256, 0, stream>>>(tgt, perm, boff);
    build_e2<<<(224 * 128 + 255) / 256, 256, 0, stream>>>(emb, E2);
    reorder_w2<<<(32 * 2048 + 255) / 256, 256, 0, stream>>>(cx2W, w2r);
    reorder_w3<<<(32 * 96 + 255) / 256, 256, 0, stream>>>(cx3W, w3r);
    wagg_acc4<<<dim3(256, 8), 256, 0, stream>>>(cx1W, perm, boff, Wagg);

    // conv1: c1[b] (256x121) = Wagg[b] (256x224) @ E2 (224x128), bias per row
    gemm(0, Wagg, E2, c1, cx1b, 256, 121, 224, 224, 128, 128,
         57344LL, 0LL, 32768LL, 512, 2, 0, 0, 0);
    // conv2: c2[b] (32x114) = w2r (32x2048) @ im2col(c1[b]),  k = kk*256+ci
    gemm(1, w2r, c1, c2, cx2b, 32, 114, 2048, 2048, 128, 128,
         0LL, 32768LL, 4096LL, 512, 2, 0, 255, 8);
    // conv3: c3[b] (32x112) = w3r (32x96) @ im2col(c2[b]),    k = kk*32+ci
    gemm(1, w3r, c2, c3, cx3b, 32, 112, 96, 96, 128, 112,
         0LL, 4096LL, 3584LL, 512, 2, 0, 31, 5);
    // xt = c3 (512x3584) @ fxtW -> zc cols 128..255
    gemm(0, c3, fxtW, zc + 128, fxtb, 512, 128, 3584, 3584, 128, 384,
         0, 0, 0, 1, 1, 0, 0, 0);

    // ---------- head ----------
    gemm(0, zc, f1W, zc1, f1b, 512, 1024, 384, 384, 1024, 1024, 0, 0, 0, 1, 1, 1, 0, 0);
    gemm(0, zc1, f2W, zc2, f2b, 512, 512, 1024, 1024, 512, 512, 0, 0, 0, 1, 1, 1, 0, 0);
    final_dot<<<512, 256, 0, stream>>>(zc2, oW, ob, outp);
}

// Round 7
// 1942.409 us; speedup vs baseline: 2.2408x; 1.1755x over previous
//
#include <hip/hip_runtime.h>
#include <cstdint>
#include <cstddef>

#define N_ATOM 65536
#define E_ATOM 262144
#define N_CLQ  32768
#define E_CLQ  131072
#define BSZ    512
#define SEQ    1000

typedef __attribute__((ext_vector_type(8))) short short8;
typedef __attribute__((ext_vector_type(4))) float f32x4;

__device__ __forceinline__ unsigned short f2bf(float x) {
    unsigned int u = __float_as_uint(x);
    u += 0x7FFFu + ((u >> 16) & 1u);          // round-to-nearest-even
    return (unsigned short)(u >> 16);
}

// ======================= bf16 MFMA GEMM =======================
// C[g] = A[g] (MxK fp32 row-major) @ B[g] (KxN fp32) + bias, optional relu.
// POLICY 0: B[k][n] = Bg[k*ldb + n]
// POLICY 1: B[k][n] = Bg[(k & cmask)*ldb + n + (k >> cshift)]  (conv im2col view)
// Block: 256 thr = 4 waves (2x2), wave tile 32x32 (2x2 mfma 16x16x32), block tile 64x64.
template<int POLICY>
__global__ __launch_bounds__(256)
void gemm_mf(const float* __restrict__ A, const float* __restrict__ B,
             float* __restrict__ C, const float* __restrict__ bias,
             int M, int N, int K, int lda, int ldb, int ldc,
             long long sA, long long sB, long long sC,
             int biasMode, int doRelu, int cmask, int cshift)
{
    __shared__ __align__(16) unsigned short As[64][40];  // [m][k] pad 40 (80B rows)
    __shared__ __align__(16) unsigned short Bs[64][40];  // [n][k] (transposed in)
    const int g = blockIdx.z;
    const float* __restrict__ Ag = A + (long long)g * sA;
    const float* __restrict__ Bg = B + (long long)g * sB;
    float* __restrict__ Cg = C + (long long)g * sC;
    const int gm0 = blockIdx.y * 64, gn0 = blockIdx.x * 64;
    const int t = threadIdx.x;
    const int lane = t & 63, wv = t >> 6, wm = wv >> 1, wn = wv & 1;
    const int lr = lane & 15, kb = (lane >> 4) * 8;
    const int am = t >> 2,  ak = (t & 3) * 8;    // A stager: row am, 8 k's at ak
    const int bn = t & 63,  bk = (t >> 6) * 8;   // B stager: col bn, 8 k's at bk

    f32x4 acc[2][2] = {};

    for (int k0 = 0; k0 < K; k0 += 32) {
        { // stage A tile (fp32 -> bf16)
            int gm = gm0 + am;
            unsigned int p[4];
#pragma unroll
            for (int j2 = 0; j2 < 4; j2++) {
                float v0 = 0.f, v1 = 0.f;
                int gk0 = k0 + ak + j2 * 2, gk1 = gk0 + 1;
                if (gm < M) {
                    if (gk0 < K) v0 = Ag[(long long)gm * lda + gk0];
                    if (gk1 < K) v1 = Ag[(long long)gm * lda + gk1];
                }
                p[j2] = (unsigned int)f2bf(v0) | ((unsigned int)f2bf(v1) << 16);
            }
            *(uint4*)&As[am][ak] = make_uint4(p[0], p[1], p[2], p[3]);
        }
        { // stage B tile transposed (fp32 -> bf16), coalesced along n
            int gn = gn0 + bn;
            unsigned int p[4];
#pragma unroll
            for (int j2 = 0; j2 < 4; j2++) {
                float v0 = 0.f, v1 = 0.f;
                int gk0 = k0 + bk + j2 * 2, gk1 = gk0 + 1;
                if (gn < N) {
                    if (gk0 < K)
                        v0 = (POLICY == 0) ? Bg[(long long)gk0 * ldb + gn]
                                           : Bg[(long long)(gk0 & cmask) * ldb + gn + (gk0 >> cshift)];
                    if (gk1 < K)
                        v1 = (POLICY == 0) ? Bg[(long long)gk1 * ldb + gn]
                                           : Bg[(long long)(gk1 & cmask) * ldb + gn + (gk1 >> cshift)];
                }
                p[j2] = (unsigned int)f2bf(v0) | ((unsigned int)f2bf(v1) << 16);
            }
            *(uint4*)&Bs[bn][bk] = make_uint4(p[0], p[1], p[2], p[3]);
        }
        __syncthreads();
        short8 a0 = __builtin_bit_cast(short8, *(const uint4*)&As[wm * 32 + lr][kb]);
        short8 a1 = __builtin_bit_cast(short8, *(const uint4*)&As[wm * 32 + 16 + lr][kb]);
        short8 b0 = __builtin_bit_cast(short8, *(const uint4*)&Bs[wn * 32 + lr][kb]);
        short8 b1 = __builtin_bit_cast(short8, *(const uint4*)&Bs[wn * 32 + 16 + lr][kb]);
        acc[0][0] = __builtin_amdgcn_mfma_f32_16x16x32_bf16(a0, b0, acc[0][0], 0, 0, 0);
        acc[0][1] = __builtin_amdgcn_mfma_f32_16x16x32_bf16(a0, b1, acc[0][1], 0, 0, 0);
        acc[1][0] = __builtin_amdgcn_mfma_f32_16x16x32_bf16(a1, b0, acc[1][0], 0, 0, 0);
        acc[1][1] = __builtin_amdgcn_mfma_f32_16x16x32_bf16(a1, b1, acc[1][1], 0, 0, 0);
        __syncthreads();
    }

#pragma unroll
    for (int fm = 0; fm < 2; fm++) {
#pragma unroll
        for (int ri = 0; ri < 4; ri++) {
            int row = gm0 + wm * 32 + fm * 16 + (lane >> 4) * 4 + ri;
            if (row >= M) continue;
#pragma unroll
            for (int fn = 0; fn < 2; fn++) {
                int col = gn0 + wn * 32 + fn * 16 + lr;
                if (col >= N) continue;
                float v = acc[fm][fn][ri];
                if (biasMode == 1)      v += bias[col];
                else if (biasMode == 2) v += bias[row];
                if (doRelu) v = fmaxf(v, 0.f);
                Cg[(long long)row * ldc + col] = v;
            }
        }
    }
}

// ======================= GCN helpers (CSR gather form) =======================
__global__ void count_deg(const int* __restrict__ dst, int E, int* __restrict__ deg)
{
    int i = blockIdx.x * 256 + threadIdx.x;
    if (i < E) atomicAdd(&deg[dst[i]], 1);
}

__global__ void make_dis(const int* __restrict__ deg, float* __restrict__ dis, int n)
{
    int i = blockIdx.x * 256 + threadIdx.x;
    if (i < n) dis[i] = rsqrtf((float)(deg[i] + 1));  // +1 self-loop
}

// exclusive scan of deg[n] -> off[n+1], single block, 256 threads, n % 256 == 0
__global__ __launch_bounds__(256)
void scan_offsets(const int* __restrict__ deg, int* __restrict__ off, int n)
{
    __shared__ int part[256];
    int t = threadIdx.x;
    int chunk = n / 256;
    int s = 0;
    for (int i = 0; i < chunk; i++) s += deg[t * chunk + i];
    part[t] = s;
    __syncthreads();
    if (t == 0) {
        int r = 0;
        for (int j = 0; j < 256; j++) { int x = part[j]; part[j] = r; r += x; }
        off[n] = r;
    }
    __syncthreads();
    int r = part[t];
    for (int i = 0; i < chunk; i++) {
        off[t * chunk + i] = r;
        r += deg[t * chunk + i];
    }
}

// csr[off[d] + slot] = s for each edge (slot via atomic counter; order irrelevant)
__global__ void csr_fill(const int* __restrict__ ei, int E,
                         const int* __restrict__ off, int* __restrict__ cur,
                         int* __restrict__ csr)
{
    int i = blockIdx.x * 256 + threadIdx.x;
    if (i >= E) return;
    int s = ei[i], d = ei[E + i];
    int p = atomicAdd(&cur[d], 1);
    csr[off[d] + p] = s;
}

// fused aggregation: out[v] = dis[v]^2 * h[v] + sum_{s in N(v)} dis[v]*dis[s]*h[s]
// one wave per row, gather form, no atomics
template<int F>
__global__ __launch_bounds__(256)
void agg_gather(const float* __restrict__ tin, const float* __restrict__ dis,
                const int* __restrict__ offs, const int* __restrict__ csr,
                float* __restrict__ out, int n)
{
    constexpr int NS = (F + 63) / 64;
    int v = blockIdx.x * 4 + (threadIdx.x >> 6);
    if (v >= n) return;
    int lane = threadIdx.x & 63;
    float dv = dis[v];
    float acc[NS];
    const float* tv = tin + (size_t)v * F;
#pragma unroll
    for (int k = 0; k < NS; k++) {
        int f = k * 64 + lane;
        acc[k] = (f < F) ? dv * dv * tv[f] : 0.f;
    }
    int o0 = offs[v], o1 = offs[v + 1];
    for (int j = o0; j < o1; j++) {
        int s = csr[j];
        float w = dv * dis[s];
        const float* ts = tin + (size_t)s * F;
#pragma unroll
        for (int k = 0; k < NS; k++) {
            int f = k * 64 + lane;
            if (f < F) acc[k] += w * ts[f];
        }
    }
    float* ov = out + (size_t)v * F;
#pragma unroll
    for (int k = 0; k < NS; k++) {
        int f = k * 64 + lane;
        if (f < F) ov[f] = acc[k];
    }
}

// segment max over CONTIGUOUS row ranges (batch[v] = v / rowsPerB by construction).
// grid (B, colChunks), block 128; coalesced column reads, no atomics, no init needed.
__global__ __launch_bounds__(128)
void pool_max2(const float* __restrict__ h, float* __restrict__ g,
               int F, int rows, int colChunk)
{
    int b = blockIdx.x;
    int t = threadIdx.x;
    if (t >= colChunk) return;
    int col = blockIdx.y * colChunk + t;
    if (col >= F) return;
    const float* hb = h + (size_t)b * rows * F;
    float m = 0.f;  // inputs are post-relu (>= 0)
    for (int r = 0; r < rows; ++r) m = fmaxf(m, hb[(size_t)r * F + col]);
    g[(size_t)b * F + col] = m;
}

// ======================= conv branch helpers =======================
__global__ void build_e2(const float* __restrict__ emb, float* __restrict__ e2)
{
    int idx = blockIdx.x * 256 + threadIdx.x;
    if (idx >= 224 * 128) return;
    int kf = idx >> 7, l = idx & 127;
    int v = kf >> 3, k = kf & 7;
    e2[idx] = (v < 26 && (l + k) < 128) ? emb[v * 128 + l + k] : 0.f;
}

// w1r[co*8+k][ci] = bf16(cx1W[co][ci][k]), zero-padded to ci<1024 (2048 x 1024 bf16)
__global__ void reorder_w1(const float* __restrict__ w, unsigned short* __restrict__ wr)
{
    int idx = blockIdx.x * 256 + threadIdx.x;
    if (idx >= 2048 * 1024) return;
    int r = idx >> 10, ci = idx & 1023;
    int co = r >> 3, k = r & 7;
    wr[idx] = (ci < SEQ) ? f2bf(w[(size_t)co * 8000 + ci * 8 + k]) : (unsigned short)0;
}

__global__ void reorder_w2(const float* __restrict__ w, float* __restrict__ wr)
{
    int idx = blockIdx.x * 256 + threadIdx.x;
    if (idx >= 32 * 2048) return;
    int co = idx >> 11, kf = idx & 2047;
    int k = kf >> 8, ci = kf & 255;
    wr[idx] = w[(co * 256 + ci) * 8 + k];
}

__global__ void reorder_w3(const float* __restrict__ w, float* __restrict__ wr)
{
    int idx = blockIdx.x * 256 + threadIdx.x;
    if (idx >= 32 * 96) return;
    int co = idx / 96, kf = idx % 96;
    int k = kf / 32, ci = kf % 32;
    wr[idx] = w[(co * 32 + ci) * 3 + k];
}

// ======================= Wagg as one-hot MFMA GEMM =======================
// Per b-pair: C (2048 x 64) = w1r (2048 x 1024 bf16) @ [O_b0 | O_b1],
// O_b[ci][v] = 1[tgt[b][ci] == v]. C[r=co*8+k][v] scattered to Wagg[b][co][v*8+k].
// Block 256 thr = 4 waves (2 m-halves x 2 b-halves), wave tile 64x32.
// Grid (16 m-tiles, 256 b-pairs). K = 1024 (padded), 16 steps of 64, fully unrolled
// so per-step tgt register indices are compile-time (rule: no dynamic reg indexing).
__global__ __launch_bounds__(256)
void conv1_wagg_mf(const unsigned short* __restrict__ w1r,
                   const int* __restrict__ tgt,
                   float* __restrict__ wagg)
{
    __shared__ __align__(16) unsigned short As[128][72];    // [m][k], pad 72
    __shared__ __align__(16) unsigned short OT[2][32][72];  // [half][v][k], pad 72
    unsigned int* OT32 = (unsigned int*)&OT[0][0][0];       // 2*32*36 = 2304 words

    const int t = threadIdx.x;
    const int m0 = blockIdx.x * 128;
    const int b0 = blockIdx.y * 2;
    const int lane = t & 63, wv = t >> 6, wm = wv >> 1, wn = wv & 1;
    const int lr = lane & 15, kb = (lane >> 4) * 8;
    const int am = t >> 1, ak0 = (t & 1) * 32;              // A stager

    // preload tgt for both b's into registers (accessed with compile-time p below)
    int r0p[4], r1p[4];
#pragma unroll
    for (int p = 0; p < 4; p++) {
        int j = p * 256 + t;
        r0p[p] = (j < SEQ) ? tgt[(size_t)b0 * SEQ + j] : 0;
        r1p[p] = (j < SEQ) ? tgt[(size_t)(b0 + 1) * SEQ + j] : 0;
    }

    f32x4 acc[4][2] = {};

#pragma unroll
    for (int s = 0; s < 16; s++) {
        __syncthreads();  // previous step's LDS fully consumed
        { // stage A (plain bf16 copy, no conversion) + zero OT
            const unsigned short* src = w1r + (size_t)(m0 + am) * 1024 + s * 64 + ak0;
#pragma unroll
            for (int j = 0; j < 4; j++)
                *(uint4*)&As[am][ak0 + j * 8] = *(const uint4*)(src + j * 8);
#pragma unroll
            for (int i = 0; i < 9; i++) OT32[i * 256 + t] = 0u;
        }
        __syncthreads();
        { // scatter one-hot entries (threads owning this 64-slice of tgt)
            const int p = s >> 2;                 // compile-time (loop unrolled)
            int rel = t - 64 * (s & 3);
            if (rel >= 0 && rel < 64 && (s * 64 + rel) < SEQ) {
                OT[0][r0p[p] & 31][rel] = 0x3F80; // bf16 1.0 (tgt in [0,26))
                OT[1][r1p[p] & 31][rel] = 0x3F80;
            }
        }
        __syncthreads();
        { // 16 MFMA per wave
            short8 a[4][2], bf[2][2];
#pragma unroll
            for (int fm = 0; fm < 4; fm++)
#pragma unroll
                for (int ks = 0; ks < 2; ks++)
                    a[fm][ks] = __builtin_bit_cast(short8,
                        *(const uint4*)&As[wm * 64 + fm * 16 + lr][kb + ks * 32]);
#pragma unroll
            for (int fn = 0; fn < 2; fn++)
#pragma unroll
                for (int ks = 0; ks < 2; ks++)
                    bf[fn][ks] = __builtin_bit_cast(short8,
                        *(const uint4*)&OT[wn][fn * 16 + lr][kb + ks * 32]);
#pragma unroll
            for (int fm = 0; fm < 4; fm++)
#pragma unroll
                for (int fn = 0; fn < 2; fn++)
#pragma unroll
                    for (int ks = 0; ks < 2; ks++)
                        acc[fm][fn] = __builtin_amdgcn_mfma_f32_16x16x32_bf16(
                            a[fm][ks], bf[fn][ks], acc[fm][fn], 0, 0, 0);
        }
    }

    // epilogue: C[r][v] -> Wagg[b0+wn][co=r>>3][v*8 + (r&7)], v < 28
    const int b = b0 + wn;
#pragma unroll
    for (int fm = 0; fm < 4; fm++) {
#pragma unroll
        for (int ri = 0; ri < 4; ri++) {
            int r = m0 + wm * 64 + fm * 16 + (lane >> 4) * 4 + ri;
            int co = r >> 3, k = r & 7;
#pragma unroll
            for (int fn = 0; fn < 2; fn++) {
                int v = fn * 16 + lr;
                if (v < 28)
                    wagg[((size_t)b * 256 + co) * 224 + v * 8 + k] = acc[fm][fn][ri];
            }
        }
    }
}

// ======================= head =======================
__global__ __launch_bounds__(256)
void final_dot(const float* __restrict__ z, const float* __restrict__ w,
               const float* __restrict__ ob, float* __restrict__ out)
{
    int b = blockIdx.x;
    float s = 0.f;
    for (int j = threadIdx.x; j < 512; j += 256) s += z[b * 512 + j] * w[j];
    for (int off = 32; off; off >>= 1) s += __shfl_down(s, off, 64);
    __shared__ float red[4];
    if ((threadIdx.x & 63) == 0) red[threadIdx.x >> 6] = s;
    __syncthreads();
    if (threadIdx.x == 0) out[b] = red[0] + red[1] + red[2] + red[3] + ob[0];
}

// ======================= host =======================
extern "C" void kernel_launch(void* const* d_in, const int* in_sizes, int n_in,
                              void* d_out, int out_size, void* d_ws, size_t ws_size,
                              hipStream_t stream)
{
    const float* x      = (const float*)d_in[0];
    const int*   ei     = (const int*)d_in[1];
    const float* cx     = (const float*)d_in[3];
    const int*   cei    = (const int*)d_in[4];
    const int*   tgt    = (const int*)d_in[6];
    const float* dW1 = (const float*)d_in[7];   const float* db1 = (const float*)d_in[8];
    const float* dW2 = (const float*)d_in[9];   const float* db2 = (const float*)d_in[10];
    const float* dW3 = (const float*)d_in[11];  const float* db3 = (const float*)d_in[12];
    const float* fcg1W = (const float*)d_in[13]; const float* fcg1b = (const float*)d_in[14];
    const float* fcg2W = (const float*)d_in[15]; const float* fcg2b = (const float*)d_in[16];
    const float* cW1 = (const float*)d_in[17];  const float* cb1 = (const float*)d_in[18];
    const float* cW2 = (const float*)d_in[19];  const float* cb2 = (const float*)d_in[20];
    const float* cW3 = (const float*)d_in[21];  const float* cb3 = (const float*)d_in[22];
    const float* cg1W = (const float*)d_in[23]; const float* cg1b = (const float*)d_in[24];
    const float* cg2W = (const float*)d_in[25]; const float* cg2b = (const float*)d_in[26];
    const float* emb  = (const float*)d_in[27];
    const float* cx1W = (const float*)d_in[28]; const float* cx1b = (const float*)d_in[29];
    const float* cx2W = (const float*)d_in[30]; const float* cx2b = (const float*)d_in[31];
    const float* cx3W = (const float*)d_in[32]; const float* cx3b = (const float*)d_in[33];
    const float* fxtW = (const float*)d_in[34]; const float* fxtb = (const float*)d_in[35];
    const float* f1W  = (const float*)d_in[36]; const float* f1b  = (const float*)d_in[37];
    const float* f2W  = (const float*)d_in[38]; const float* f2b  = (const float*)d_in[39];
    const float* oW   = (const float*)d_in[40]; const float* ob   = (const float*)d_in[41];

    char* w8 = (char*)d_ws;
    // GCN phase: bufA (agg out, F<=202) 0..52,953,088; bufB (gemm out, F<=404) ..158,859,264
    float* bufA = (float*)(w8);
    float* bufB = (float*)(w8 + 52953088);
    // CSR arrays (GCN phase only; conv c1 region overlaps them later, stream-ordered safe)
    int*   off_a = (int*)(w8 + 160000000);           // 65537*4  ..160,262,148
    int*   cur_a = (int*)(w8 + 160262400);           // 65536*4  ..160,524,544
    int*   csr_a = (int*)(w8 + 160524544);           // 262144*4 ..161,573,120
    int*   off_c = (int*)(w8 + 161573120);           // 32769*4  ..161,704,196
    int*   cur_c = (int*)(w8 + 161704448);           // 32768*4  ..161,835,520
    int*   csr_c = (int*)(w8 + 161835520);           // 131072*4 ..162,359,808
    // conv phase (after GCN done): Wagg at 0, c1/c2/c3 behind it
    float* Wagg = (float*)(w8);                      // 512*256*224*4 = 117,440,512
    float* c1   = (float*)(w8 + 117440512);          // 512*256*128*4 = 67,108,864
    float* c2   = (float*)(w8 + 184549376);          // 512*32*128*4  =  8,388,608
    float* c3   = (float*)(w8 + 192937984);          // 512*112*32*4  =  7,340,032
    unsigned short* w1r = (unsigned short*)(w8 + 200279040);  // 2048*1024*2 = 4,194,304
    size_t off  = 211812352;
    auto take = [&](size_t bytes) -> void* {
        void* p = w8 + off;
        off += (bytes + 255) & ~(size_t)255;
        return p;
    };
    float* g0  = (float*)take(512 * 404 * 4);
    float* q0  = (float*)take(512 * 140 * 4);
    float* gh  = (float*)take(512 * 1024 * 4);
    float* qh  = (float*)take(512 * 1024 * 4);
    float* zc  = (float*)take(512 * 384 * 4);
    float* zc1 = (float*)take(512 * 1024 * 4);
    float* zc2 = (float*)take(512 * 512 * 4);
    int*   dega = (int*)take(N_ATOM * 4);
    float* disa = (float*)take(N_ATOM * 4);
    int*   degc = (int*)take(N_CLQ * 4);
    float* disc = (float*)take(N_CLQ * 4);
    float* E2   = (float*)take(224 * 128 * 4);
    float* w2r  = (float*)take(32 * 2048 * 4);
    float* w3r  = (float*)take(32 * 96 * 4);
    float* outp = (float*)d_out;

    auto gemm = [&](int policy, const float* A, const float* B, float* C,
                    const float* bias, int M, int N, int K,
                    int lda, int ldb, int ldc,
                    long long sA, long long sB, long long sC, int G,
                    int biasMode, int relu, int cmask, int cshift) {
        dim3 grid((N + 63) / 64, (M + 63) / 64, G);
        if (policy == 0)
            hipLaunchKernelGGL((gemm_mf<0>), grid, dim3(256), 0, stream,
                A, B, C, bias, M, N, K, lda, ldb, ldc, sA, sB, sC, biasMode, relu, cmask, cshift);
        else
            hipLaunchKernelGGL((gemm_mf<1>), grid, dim3(256), 0, stream,
                A, B, C, bias, M, N, K, lda, ldb, ldc, sA, sB, sC, biasMode, relu, cmask, cshift);
    };

    // ---------- init ----------
    hipMemsetAsync(dega, 0, N_ATOM * 4, stream);
    hipMemsetAsync(degc, 0, N_CLQ * 4, stream);
    hipMemsetAsync(cur_a, 0, N_ATOM * 4, stream);
    hipMemsetAsync(cur_c, 0, N_CLQ * 4, stream);

    // ---------- CSR build (atoms + cliques) ----------
    count_deg<<<(E_ATOM + 255) / 256, 256, 0, stream>>>(ei + E_ATOM, E_ATOM, dega);
    make_dis<<<(N_ATOM + 255) / 256, 256, 0, stream>>>(dega, disa, N_ATOM);
    scan_offsets<<<1, 256, 0, stream>>>(dega, off_a, N_ATOM);
    csr_fill<<<(E_ATOM + 255) / 256, 256, 0, stream>>>(ei, E_ATOM, off_a, cur_a, csr_a);

    count_deg<<<(E_CLQ + 255) / 256, 256, 0, stream>>>(cei + E_CLQ, E_CLQ, degc);
    make_dis<<<(N_CLQ + 255) / 256, 256, 0, stream>>>(degc, disc, N_CLQ);
    scan_offsets<<<1, 256, 0, stream>>>(degc, off_c, N_CLQ);
    csr_fill<<<(E_CLQ + 255) / 256, 256, 0, stream>>>(cei, E_CLQ, off_c, cur_c, csr_c);

    // ---------- atom GCN branch (gather agg at F_in, bias+relu fused into GEMM) ----------
    agg_gather<101><<<N_ATOM / 4, 256, 0, stream>>>(x, disa, off_a, csr_a, bufA, N_ATOM);
    gemm(0, bufA, dW1, bufB, db1, N_ATOM, 101, 101, 101, 101, 101, 0, 0, 0, 1, 1, 1, 0, 0);

    agg_gather<101><<<N_ATOM / 4, 256, 0, stream>>>(bufB, disa, off_a, csr_a, bufA, N_ATOM);
    gemm(0, bufA, dW2, bufB, db2, N_ATOM, 202, 101, 101, 202, 202, 0, 0, 0, 1, 1, 1, 0, 0);

    agg_gather<202><<<N_ATOM / 4, 256, 0, stream>>>(bufB, disa, off_a, csr_a, bufA, N_ATOM);
    gemm(0, bufA, dW3, bufB, db3, N_ATOM, 404, 202, 202, 404, 404, 0, 0, 0, 1, 1, 1, 0, 0);

    pool_max2<<<dim3(512, 4), 128, 0, stream>>>(bufB, g0, 404, 128, 101);
    gemm(0, g0, fcg1W, gh, fcg1b, 512, 1024, 404, 404, 1024, 1024, 0, 0, 0, 1, 1, 1, 0, 0);
    gemm(0, gh, fcg2W, zc + 0, fcg2b, 512, 128, 1024, 1024, 128, 384, 0, 0, 0, 1, 1, 0, 0, 0);

    // ---------- clique GCN branch ----------
    agg_gather<35><<<N_CLQ / 4, 256, 0, stream>>>(cx, disc, off_c, csr_c, bufA, N_CLQ);
    gemm(0, bufA, cW1, bufB, cb1, N_CLQ, 35, 35, 35, 35, 35, 0, 0, 0, 1, 1, 1, 0, 0);

    agg_gather<35><<<N_CLQ / 4, 256, 0, stream>>>(bufB, disc, off_c, csr_c, bufA, N_CLQ);
    gemm(0, bufA, cW2, bufB, cb2, N_CLQ, 70, 35, 35, 70, 70, 0, 0, 0, 1, 1, 1, 0, 0);

    agg_gather<70><<<N_CLQ / 4, 256, 0, stream>>>(bufB, disc, off_c, csr_c, bufA, N_CLQ);
    gemm(0, bufA, cW3, bufB, cb3, N_CLQ, 140, 70, 70, 140, 140, 0, 0, 0, 1, 1, 1, 0, 0);

    pool_max2<<<dim3(512, 2), 128, 0, stream>>>(bufB, q0, 140, 64, 70);
    gemm(0, q0, cg1W, qh, cg1b, 512, 1024, 140, 140, 1024, 1024, 0, 0, 0, 1, 1, 1, 0, 0);
    gemm(0, qh, cg2W, zc + 256, cg2b, 512, 128, 1024, 1024, 128, 384, 0, 0, 0, 1, 1, 0, 0, 0);

    // ---------- protein conv branch (vocab-factorized conv1 via one-hot MFMA) ----------
    build_e2<<<(224 * 128 + 255) / 256, 256, 0, stream>>>(emb, E2);
    reorder_w1<<<(2048 * 1024) / 256, 256, 0, stream>>>(cx1W, w1r);
    reorder_w2<<<(32 * 2048 + 255) / 256, 256, 0, stream>>>(cx2W, w2r);
    reorder_w3<<<(32 * 96 + 255) / 256, 256, 0, stream>>>(cx3W, w3r);
    conv1_wagg_mf<<<dim3(16, 256), 256, 0, stream>>>(w1r, tgt, Wagg);

    // conv1: c1[b] (256x121) = Wagg[b] (256x224) @ E2 (224x128), bias per row
    gemm(0, Wagg, E2, c1, cx1b, 256, 121, 224, 224, 128, 128,
         57344LL, 0LL, 32768LL, 512, 2, 0, 0, 0);
    // conv2: c2[b] (32x114) = w2r (32x2048) @ im2col(c1[b]),  k = kk*256+ci
    gemm(1, w2r, c1, c2, cx2b, 32, 114, 2048, 2048, 128, 128,
         0LL, 32768LL, 4096LL, 512, 2, 0, 255, 8);
    // conv3: c3[b] (32x112) = w3r (32x96) @ im2col(c2[b]),    k = kk*32+ci
    gemm(1, w3r, c2, c3, cx3b, 32, 112, 96, 96, 128, 112,
         0LL, 4096LL, 3584LL, 512, 2, 0, 31, 5);
    // xt = c3 (512x3584) @ fxtW -> zc cols 128..255
    gemm(0, c3, fxtW, zc + 128, fxtb, 512, 128, 3584, 3584, 128, 384,
         0, 0, 0, 1, 1, 0, 0, 0);

    // ---------- head ----------
    gemm(0, zc, f1W, zc1, f1b, 512, 1024, 384, 384, 1024, 1024, 0, 0, 0, 1, 1, 1, 0, 0);
    gemm(0, zc1, f2W, zc2, f2b, 512, 512, 1024, 1024, 512, 512, 0, 0, 0, 1, 1, 1, 0, 0);
    final_dot<<<512, 256, 0, stream>>>(zc2, oW, ob, outp);
}